// Round 14
// baseline (393.725 us; speedup 1.0000x reference)
//
#include <hip/hip_runtime.h>

#define S_LEN  1024
#define DMODEL 1024
#define NHEAD  16
#define DHEAD  64
#define MROWS  8192   // 8 sequences * 1024
#define HIDDIM 4096
#define WINR   128

typedef __attribute__((ext_vector_type(8))) short bf16x8;
typedef __attribute__((ext_vector_type(4))) float f32x4;

__device__ __forceinline__ float bf2f(unsigned short u){ return __uint_as_float(((unsigned)u) << 16); }
__device__ __forceinline__ unsigned short f2bf(float f){
  unsigned u = __float_as_uint(f);
  u += 0x7FFFu + ((u >> 16) & 1u);
  return (unsigned short)(u >> 16);
}

// async global->LDS, 16 B per lane; lds dest is wave-uniform base (lane-linear fill)
__device__ __forceinline__ void gload_lds16(const unsigned short* g, unsigned short* l){
  __builtin_amdgcn_global_load_lds((const __attribute__((address_space(1))) unsigned int*)g,
                                   (__attribute__((address_space(3))) unsigned int*)l, 16, 0, 0);
}

// ---------------- weight transpose: in f32 [R][C] -> out bf16 [C][R] ----------------
__global__ __launch_bounds__(256) void transpose_w(const float* __restrict__ in,
                                                   unsigned short* __restrict__ out,
                                                   int R, int C){
  __shared__ float tile[32][33];
  const int c0 = blockIdx.x * 32;
  const int r0 = blockIdx.y * 32;
  const int tx = threadIdx.x & 31;
  const int ty = threadIdx.x >> 5;   // 0..7
  #pragma unroll
  for (int i = 0; i < 32; i += 8)
    tile[ty + i][tx] = in[(size_t)(r0 + ty + i) * C + c0 + tx];
  __syncthreads();
  #pragma unroll
  for (int i = 0; i < 32; i += 8)
    out[(size_t)(c0 + ty + i) * R + r0 + tx] = f2bf(tile[tx][ty + i]);
}

// ---------------- LayerNorm: row per block, 4 source pointers (2048 rows each) -------
__global__ __launch_bounds__(256) void ln_kernel(const float* __restrict__ s0, const float* __restrict__ s1,
                                                 const float* __restrict__ s2, const float* __restrict__ s3,
                                                 const float* __restrict__ g, const float* __restrict__ b,
                                                 unsigned short* __restrict__ out){
  const int row = blockIdx.x;
  const int t = threadIdx.x;
  const float* src = (row < 2048) ? s0 : (row < 4096) ? s1 : (row < 6144) ? s2 : s3;
  const float* x = src + (size_t)(row & 2047) * DMODEL;
  float4 v = *(const float4*)&x[t * 4];
  float sum  = v.x + v.y + v.z + v.w;
  float ssum = v.x*v.x + v.y*v.y + v.z*v.z + v.w*v.w;
  #pragma unroll
  for (int o = 32; o > 0; o >>= 1){
    sum  += __shfl_down(sum, o);
    ssum += __shfl_down(ssum, o);
  }
  __shared__ float red[8];
  if ((t & 63) == 0){ red[t >> 6] = sum; red[4 + (t >> 6)] = ssum; }
  __syncthreads();
  sum  = red[0] + red[1] + red[2] + red[3];
  ssum = red[4] + red[5] + red[6] + red[7];
  const float mu  = sum * (1.f / DMODEL);
  const float var = ssum * (1.f / DMODEL) - mu * mu;
  const float rs  = rsqrtf(var + 1e-5f);
  float4 gg = *(const float4*)&g[t * 4];
  float4 bb = *(const float4*)&b[t * 4];
  ushort4 o;
  o.x = f2bf((v.x - mu) * rs * gg.x + bb.x);
  o.y = f2bf((v.y - mu) * rs * gg.y + bb.y);
  o.z = f2bf((v.z - mu) * rs * gg.z + bb.z);
  o.w = f2bf((v.w - mu) * rs * gg.w + bb.w);
  *(ushort4*)&out[(size_t)row * DMODEL + t * 4] = o;
}

// ---------------- banded flash attention, MFMA 16x16x32, swapped QK^T ----------------
__global__ __launch_bounds__(256) void attn_kernel(const unsigned short* __restrict__ qh,
                                                   const unsigned short* __restrict__ kh,
                                                   const unsigned short* __restrict__ vt,
                                                   unsigned short* __restrict__ ctx){
  __shared__ unsigned short Ks[64 * 64];      // [key][d]  (d XOR-swizzled by key&7)
  __shared__ unsigned short Vs[64 * 64];      // [d][key]  (key XOR-swizzled by d&7)
  __shared__ unsigned short Ps[4][16 * 64];   // per-wave P [q][key] (key XOR by q&7)
  const int bx = blockIdx.x;
  const int qt = bx & 15, hd = (bx >> 4) & 15, n = bx >> 8;
  const int q0 = qt * 64;
  const int tid = threadIdx.x, lane = tid & 63, w = tid >> 6;
  const int hi = lane >> 4, lo = lane & 15;
  const size_t headoff = (size_t)(n * NHEAD + hd) * S_LEN * DHEAD;
  const unsigned short* kb = kh + headoff;
  const unsigned short* vb = vt + headoff;    // [64 d][1024 s]

  const int qg = q0 + w * 16 + lo;
  bf16x8 bq0 = *(const bf16x8*)(qh + headoff + (size_t)qg * DHEAD + hi * 8);
  bf16x8 bq1 = *(const bf16x8*)(qh + headoff + (size_t)qg * DHEAD + 32 + hi * 8);

  f32x4 oa[4];
  const f32x4 zero = {0.f, 0.f, 0.f, 0.f};
  #pragma unroll
  for (int dj = 0; dj < 4; dj++) oa[dj] = zero;
  float m = -20.f, lsum = 0.f;

  int t_first = q0 - WINR; if (t_first < 0) t_first = 0;
  int t_last  = q0 + 63 + WINR; if (t_last > S_LEN - 1) t_last = S_LEN - 1;

  const int sk = ((lane & 7) ^ (lane >> 3)) * 8;
  const int px = (lo & 7) * 8;

  for (int tb = t_first; tb <= t_last; tb += 64){
    __syncthreads();
    #pragma unroll
    for (int p = 0; p < 2; p++){
      const int r = w * 16 + p * 8 + (lane >> 3);
      gload_lds16(kb + (size_t)(tb + r) * DHEAD + sk, Ks + (w * 16 + p * 8) * 64);
      gload_lds16(vb + (size_t)r * S_LEN + tb + sk, Vs + (w * 16 + p * 8) * 64);
    }
    __syncthreads();

    f32x4 sc[4];
    #pragma unroll
    for (int j = 0; j < 4; j++){
      const int row = j * 16 + lo;
      bf16x8 ak0 = *(const bf16x8*)&Ks[row * 64 + ((hi * 8) ^ px)];
      bf16x8 ak1 = *(const bf16x8*)&Ks[row * 64 + ((32 + hi * 8) ^ px)];
      sc[j] = __builtin_amdgcn_mfma_f32_16x16x32_bf16(ak0, bq0, zero, 0, 0, 0);
      sc[j] = __builtin_amdgcn_mfma_f32_16x16x32_bf16(ak1, bq1, sc[j], 0, 0, 0);
    }

    float mloc = -1e30f;
    #pragma unroll
    for (int j = 0; j < 4; j++)
      #pragma unroll
      for (int r = 0; r < 4; r++){
        const int key = tb + j * 16 + hi * 4 + r;
        float s = sc[j][r] * 0.125f;
        s = ((unsigned)(key - qg + WINR) <= 2u * WINR) ? s : -1e9f;
        sc[j][r] = s;
        mloc = fmaxf(mloc, s);
      }
    mloc = fmaxf(mloc, __shfl_xor(mloc, 16));
    mloc = fmaxf(mloc, __shfl_xor(mloc, 32));
    const float nm = fmaxf(m, mloc);
    const float scale = __expf(m - nm);
    m = nm;
    float psum = 0.f;
    #pragma unroll
    for (int j = 0; j < 4; j++){
      float p0 = __expf(sc[j][0] - nm), p1 = __expf(sc[j][1] - nm);
      float p2 = __expf(sc[j][2] - nm), p3 = __expf(sc[j][3] - nm);
      psum += (p0 + p1) + (p2 + p3);
      ushort4 pw = { f2bf(p0), f2bf(p1), f2bf(p2), f2bf(p3) };
      *(ushort4*)&Ps[w][lo * 64 + ((hi * 4 + 16 * j) ^ px)] = pw;
    }
    psum += __shfl_xor(psum, 16);
    psum += __shfl_xor(psum, 32);
    lsum = lsum * scale + psum;

    float scr[4];
    #pragma unroll
    for (int r = 0; r < 4; r++) scr[r] = __shfl(scale, (lane & 48) + hi * 4 + r);
    #pragma unroll
    for (int dj = 0; dj < 4; dj++)
      #pragma unroll
      for (int r = 0; r < 4; r++) oa[dj][r] *= scr[r];

    bf16x8 pa0 = *(const bf16x8*)&Ps[w][lo * 64 + ((hi * 8) ^ px)];
    bf16x8 pa1 = *(const bf16x8*)&Ps[w][lo * 64 + ((32 + hi * 8) ^ px)];
    #pragma unroll
    for (int dj = 0; dj < 4; dj++){
      const int dr = dj * 16 + lo;
      bf16x8 bv0 = *(const bf16x8*)&Vs[dr * 64 + ((hi * 8) ^ px)];
      bf16x8 bv1 = *(const bf16x8*)&Vs[dr * 64 + ((32 + hi * 8) ^ px)];
      oa[dj] = __builtin_amdgcn_mfma_f32_16x16x32_bf16(pa0, bv0, oa[dj], 0, 0, 0);
      oa[dj] = __builtin_amdgcn_mfma_f32_16x16x32_bf16(pa1, bv1, oa[dj], 0, 0, 0);
    }
  }

  const float inv = 1.f / lsum;
  float invr[4];
  #pragma unroll
  for (int r = 0; r < 4; r++) invr[r] = __shfl(inv, (lane & 48) + hi * 4 + r);
  #pragma unroll
  for (int dj = 0; dj < 4; dj++)
    #pragma unroll
    for (int r = 0; r < 4; r++){
      const int srow = q0 + w * 16 + hi * 4 + r;
      ctx[((size_t)(n * S_LEN + srow)) * DMODEL + hd * DHEAD + dj * 16 + lo] =
          f2bf(oa[dj][r] * invr[r]);
    }
}

// ============ 128x128 bf16 MFMA GEMM, single-buffer 32 KB (round-13 proven) =========
struct GemmP {
  const unsigned short* A;
  const unsigned short* Bt;
  int K;
  int N;
  const float* bias;
  const float* r0; const float* r1; const float* r2; const float* r3;
  unsigned short* oq; unsigned short* ok; unsigned short* ov;   // qkv (ov = V^T)
  float* of;
};

// MODE 0: qkv head scatter (LDS-staged, V transposed)
// MODE 1: +bias +residual(sel by row) -> f32 direct float4
// MODE 4: +bias +r0 -> f32 direct float4
template<int MODE>
__global__ __launch_bounds__(256, 2) void gemm_bn128(GemmP p){
  __shared__ unsigned short ldsA[128 * 64];   // 16 KB
  __shared__ unsigned short ldsB[128 * 64];   // 16 KB
  const int tid  = threadIdx.x;
  const int lane = tid & 63;
  const int w    = tid >> 6;                // 0..3
  const int lo   = lane & 15, hi = lane >> 4;
  const int l3   = lane >> 3;
  const int sk   = ((lane & 7) ^ l3) * 8;   // pre-swizzled source k offset (elems)
  const int wm   = (w >> 1) * 64;           // 2M x 2N waves
  const int wn   = (w & 1) * 64;
  const int K    = p.K;

  const int nwg = gridDim.x;
  const int cpx = nwg >> 3;
  const int bsw = ((int)blockIdx.x & 7) * cpx + ((int)blockIdx.x >> 3);
  const int ntn = p.N >> 7;
  const int m0  = (bsw / ntn) * 128;
  const int n0  = (bsw % ntn) * 128;

  f32x4 acc[4][4];
  const f32x4 zero = {0.f, 0.f, 0.f, 0.f};
  #pragma unroll
  for (int i = 0; i < 4; i++)
    #pragma unroll
    for (int j = 0; j < 4; j++) acc[i][j] = zero;

  const int NT = K >> 6;
  for (int T = 0; T < NT; T++){
    const int kb = T * 64;
    __syncthreads();             // prev-tile LDS reads done before overwrite
    #pragma unroll
    for (int c = 0; c < 4; c++){
      const int r0 = w * 32 + c * 8;        // 4 waves x 8 rows x 4 calls = 128 rows
      gload_lds16(p.A  + (size_t)(m0 + r0 + l3) * K + kb + sk, &ldsA[r0 * 64]);
      gload_lds16(p.Bt + (size_t)(n0 + r0 + l3) * K + kb + sk, &ldsB[r0 * 64]);
    }
    __syncthreads();             // drains vmcnt: this tile's stage visible to all

    #pragma unroll
    for (int kk = 0; kk < 2; kk++){
      bf16x8 af[4], bfr[4];
      #pragma unroll
      for (int i = 0; i < 4; i++){
        const int R = wm + i * 16 + lo;
        af[i] = *(const bf16x8*)&ldsA[R * 64 + (((kk * 4 + hi) ^ (R & 7)) * 8)];
      }
      #pragma unroll
      for (int j = 0; j < 4; j++){
        const int R = wn + j * 16 + lo;
        bfr[j] = *(const bf16x8*)&ldsB[R * 64 + (((kk * 4 + hi) ^ (R & 7)) * 8)];
      }
      #pragma unroll
      for (int i = 0; i < 4; i++)
        #pragma unroll
        for (int j = 0; j < 4; j++)
          acc[i][j] = __builtin_amdgcn_mfma_f32_16x16x32_bf16(bfr[j], af[i], acc[i][j], 0, 0, 0);
    }
  }

  if constexpr (MODE == 1 || MODE == 4){
    // direct coalesced f32: thread stores float4 (4 adjacent cols, one row)
    const float* rs = p.r0;
    if constexpr (MODE == 1){
      const int rblk = m0 + wm;   // uniform per wave, never straddles 2048
      rs = (rblk < 2048) ? p.r0 : (rblk < 4096) ? p.r1 : (rblk < 6144) ? p.r2 : p.r3;
    }
    #pragma unroll
    for (int i = 0; i < 4; i++){
      const int row = m0 + wm + i * 16 + lo;
      #pragma unroll
      for (int j = 0; j < 4; j++){
        const int cb = n0 + wn + j * 16 + hi * 4;
        float4 b4 = *(const float4*)&p.bias[cb];
        float4 r4;
        if constexpr (MODE == 1) r4 = *(const float4*)&rs[(size_t)(row & 2047) * DMODEL + cb];
        else                     r4 = *(const float4*)&rs[(size_t)row * DMODEL + cb];
        float4 v;
        v.x = acc[i][j][0] + b4.x + r4.x;
        v.y = acc[i][j][1] + b4.y + r4.y;
        v.z = acc[i][j][2] + b4.z + r4.z;
        v.w = acc[i][j][3] + b4.w + r4.w;
        *(float4*)&p.of[(size_t)row * DMODEL + cb] = v;
      }
    }
  } else {
    // MODE 0: LDS-staged coalesced qkv scatter (per-wave 8 KB slice spanning ldsA+ldsB)
    __syncthreads();                                  // all K-loop LDS reads done
    unsigned short* sl = &ldsA[0] + w * 4096;
    const int nseq = (m0 + wm) >> 10;                 // uniform per wave
    const int sof  = (m0 + wm) & 1023;
    const bool isV = (n0 >> 10) == 2;
    if (!isV){
      // stage [s 64][c 64], 16B-chunk XOR by row&7
      #pragma unroll
      for (int i = 0; i < 4; i++){
        const int row = i * 16 + lo;
        #pragma unroll
        for (int j = 0; j < 4; j++){
          const int c  = j * 16 + hi * 4;
          const int cb = n0 + wn + c;
          float4 b4 = *(const float4*)&p.bias[cb];
          ushort4 o = { f2bf(acc[i][j][0] + b4.x), f2bf(acc[i][j][1] + b4.y),
                        f2bf(acc[i][j][2] + b4.z), f2bf(acc[i][j][3] + b4.w) };
          *(ushort4*)&sl[row * 64 + (((c >> 3) ^ (row & 7)) * 8) + (c & 7)] = o;
        }
      }
      asm volatile("s_waitcnt lgkmcnt(0)" ::: "memory");
      __builtin_amdgcn_sched_barrier(0);
      #pragma unroll
      for (int rep = 0; rep < 8; rep++){
        const int row = rep * 8 + l3;
        const int ch  = lane & 7;
        bf16x8 val = *(const bf16x8*)&sl[row * 64 + ((ch ^ (row & 7)) * 8)];
        const int cg = n0 + wn + ch * 8;
        const int hh = (cg & 1023) >> 6, d0 = cg & 63;
        unsigned short* dst = (cg >> 10) ? p.ok : p.oq;
        *(bf16x8*)&dst[((size_t)((nseq * NHEAD + hh) * S_LEN) + sof + row) * DHEAD + d0] = val;
      }
    } else {
      // V: stage transposed [d 64][s 64], 16B-chunk XOR by d&7
      #pragma unroll
      for (int i = 0; i < 4; i++){
        const int s = i * 16 + lo;
        #pragma unroll
        for (int j = 0; j < 4; j++){
          const int cb = n0 + wn + j * 16 + hi * 4;
          float4 b4 = *(const float4*)&p.bias[cb];
          #pragma unroll
          for (int r = 0; r < 4; r++){
            const int d = j * 16 + hi * 4 + r;
            const float bv = (r == 0) ? b4.x : (r == 1) ? b4.y : (r == 2) ? b4.z : b4.w;
            sl[d * 64 + (((s >> 3) ^ (d & 7)) * 8) + (s & 7)] = f2bf(acc[i][j][r] + bv);
          }
        }
      }
      asm volatile("s_waitcnt lgkmcnt(0)" ::: "memory");
      __builtin_amdgcn_sched_barrier(0);
      #pragma unroll
      for (int rep = 0; rep < 8; rep++){
        const int d  = rep * 8 + l3;
        const int ch = lane & 7;
        bf16x8 val = *(const bf16x8*)&sl[d * 64 + ((ch ^ (d & 7)) * 8)];
        const int cg = n0 + wn + d;
        const int hh = (cg & 1023) >> 6, dd = cg & 63;
        *(bf16x8*)&p.ov[((size_t)((nseq * NHEAD + hh) * DHEAD) + dd) * S_LEN + sof + ch * 8] = val;
      }
    }
  }
}

// ============ fused SwiGLU FFN-up: silu(A@W1^T+b1) * (A@W2^T+b2) -> bf16 =============
// BM=256, BN=128, 512 threads = 8 waves (4M x 2N), per-wave 64x64 per branch
// (identical register shape to round-13). Single-buffer 64 KB LDS (one array, manual
// offsets), classic 2-syncthreads K-loop, 2 blocks/CU (16 waves). Halves A+B re-fetch.
__global__ __launch_bounds__(512, 2) void gemm_ffn(const unsigned short* __restrict__ A,
                                                   const unsigned short* __restrict__ B1t,
                                                   const unsigned short* __restrict__ B2t,
                                                   const float* __restrict__ b1,
                                                   const float* __restrict__ b2,
                                                   unsigned short* __restrict__ out){
  __shared__ unsigned short lds[32768];        // 64 KB: A[0,16384) B1[16384,24576) B2[24576,32768)
  unsigned short* ldsA  = lds;
  unsigned short* ldsB1 = lds + 16384;
  unsigned short* ldsB2 = lds + 24576;
  const int tid  = threadIdx.x;
  const int lane = tid & 63;
  const int w    = tid >> 6;                // 0..7
  const int lo   = lane & 15, hi = lane >> 4;
  const int l3   = lane >> 3;
  const int sk   = ((lane & 7) ^ l3) * 8;
  const int wm   = (w >> 1) * 64;           // 4M x 2N waves: 0,64,128,192
  const int wn   = (w & 1) * 64;            // 0,64

  const int nwg = gridDim.x;                // 1024 (32 m x 32 n)
  const int cpx = nwg >> 3;
  const int bsw = ((int)blockIdx.x & 7) * cpx + ((int)blockIdx.x >> 3);
  const int m0  = (bsw >> 5) * 256;
  const int n0  = (bsw & 31) * 128;

  f32x4 a1[4][4], a2[4][4];
  const f32x4 zero = {0.f, 0.f, 0.f, 0.f};
  #pragma unroll
  for (int i = 0; i < 4; i++)
    #pragma unroll
    for (int j = 0; j < 4; j++){ a1[i][j] = zero; a2[i][j] = zero; }

  const int NT = DMODEL >> 6;    // 16
  for (int T = 0; T < NT; T++){
    const int kb = T * 64;
    __syncthreads();             // prev-tile LDS reads done before overwrite
    #pragma unroll
    for (int c = 0; c < 4; c++){ // A: 256 rows, each call covers 64 rows (512 thr x 16B)
      const int r0 = c * 64 + w * 8;
      gload_lds16(A + (size_t)(m0 + r0 + l3) * DMODEL + kb + sk, &ldsA[r0 * 64]);
    }
    #pragma unroll
    for (int c = 0; c < 2; c++){ // B1/B2: 128 rows each
      const int r0 = c * 64 + w * 8;
      gload_lds16(B1t + (size_t)(n0 + r0 + l3) * DMODEL + kb + sk, &ldsB1[r0 * 64]);
      gload_lds16(B2t + (size_t)(n0 + r0 + l3) * DMODEL + kb + sk, &ldsB2[r0 * 64]);
    }
    __syncthreads();             // drains vmcnt: this tile's stage visible to all

    #pragma unroll
    for (int kk = 0; kk < 2; kk++){
      bf16x8 af[4], bf1[4], bf2[4];
      #pragma unroll
      for (int i = 0; i < 4; i++){
        const int R = wm + i * 16 + lo;        // 0..255
        af[i] = *(const bf16x8*)&ldsA[R * 64 + (((kk * 4 + hi) ^ (R & 7)) * 8)];
      }
      #pragma unroll
      for (int j = 0; j < 4; j++){
        const int R = wn + j * 16 + lo;        // 0..127
        const int off = R * 64 + (((kk * 4 + hi) ^ (R & 7)) * 8);
        bf1[j] = *(const bf16x8*)&ldsB1[off];
        bf2[j] = *(const bf16x8*)&ldsB2[off];
      }
      #pragma unroll
      for (int i = 0; i < 4; i++)
        #pragma unroll
        for (int j = 0; j < 4; j++){
          a1[i][j] = __builtin_amdgcn_mfma_f32_16x16x32_bf16(bf1[j], af[i], a1[i][j], 0, 0, 0);
          a2[i][j] = __builtin_amdgcn_mfma_f32_16x16x32_bf16(bf2[j], af[i], a2[i][j], 0, 0, 0);
        }
    }
  }

  // fused epilogue: LDS-staged coalesced bf16 (8 waves x 8 KB = 64 KB = whole lds)
  __syncthreads();
  unsigned short* sl = lds + w * 4096;   // per-wave [s 64][c 64]
  #pragma unroll
  for (int i = 0; i < 4; i++){
    const int row = i * 16 + lo;
    #pragma unroll
    for (int j = 0; j < 4; j++){
      const int c  = j * 16 + hi * 4;
      const int cb = n0 + wn + c;
      float4 g1 = *(const float4*)&b1[cb];
      float4 g2 = *(const float4*)&b2[cb];
      float v1[4] = { a1[i][j][0] + g1.x, a1[i][j][1] + g1.y, a1[i][j][2] + g1.z, a1[i][j][3] + g1.w };
      float v2[4] = { a2[i][j][0] + g2.x, a2[i][j][1] + g2.y, a2[i][j][2] + g2.z, a2[i][j][3] + g2.w };
      ushort4 o;
      o.x = f2bf(v1[0] / (1.f + __expf(-v1[0])) * v2[0]);
      o.y = f2bf(v1[1] / (1.f + __expf(-v1[1])) * v2[1]);
      o.z = f2bf(v1[2] / (1.f + __expf(-v1[2])) * v2[2]);
      o.w = f2bf(v1[3] / (1.f + __expf(-v1[3])) * v2[3]);
      *(ushort4*)&sl[row * 64 + (((c >> 3) ^ (row & 7)) * 8) + (c & 7)] = o;
    }
  }
  asm volatile("s_waitcnt lgkmcnt(0)" ::: "memory");
  __builtin_amdgcn_sched_barrier(0);
  #pragma unroll
  for (int rep = 0; rep < 8; rep++){
    const int row = rep * 8 + l3;            // 0..63 within wave's 64-row span
    const int ch  = lane & 7;
    bf16x8 val = *(const bf16x8*)&sl[row * 64 + ((ch ^ (row & 7)) * 8)];
    *(bf16x8*)&out[(size_t)(m0 + wm + row) * HIDDIM + n0 + wn + ch * 8] = val;
  }
}

// ------------------------------------------------------------------------------------
extern "C" void kernel_launch(void* const* d_in, const int* in_sizes, int n_in,
                              void* d_out, int out_size, void* d_ws, size_t ws_size,
                              hipStream_t stream){
  const float* fin  = (const float*)d_in[0];
  const float* vis  = (const float*)d_in[1];
  const float* txt  = (const float*)d_in[2];
  const float* aud  = (const float*)d_in[3];
  const float* ln1g = (const float*)d_in[4];
  const float* ln1b = (const float*)d_in[5];
  const float* Wqkv = (const float*)d_in[6];
  const float* bqkv = (const float*)d_in[7];
  const float* Wo   = (const float*)d_in[8];
  const float* bo   = (const float*)d_in[9];
  const float* ln2g = (const float*)d_in[10];
  const float* ln2b = (const float*)d_in[11];
  const float* W1   = (const float*)d_in[12];
  const float* b1   = (const float*)d_in[13];
  const float* W2   = (const float*)d_in[14];
  const float* b2   = (const float*)d_in[15];
  const float* W3   = (const float*)d_in[16];
  const float* b3   = (const float*)d_in[17];

  char* ws = (char*)d_ws;
  unsigned short* Wqkv_t = (unsigned short*)(ws + 0);          //  6,291,456
  unsigned short* Wo_t   = (unsigned short*)(ws + 6291456);    //  2,097,152
  unsigned short* W1t    = (unsigned short*)(ws + 8388608);    //  8,388,608
  unsigned short* W2t    = (unsigned short*)(ws + 16777216);   //  8,388,608
  unsigned short* W3t    = (unsigned short*)(ws + 25165824);   //  8,388,608
  unsigned short* h      = (unsigned short*)(ws + 33554432);   // 16,777,216
  unsigned short* qh     = (unsigned short*)(ws + 50331648);   // 16,777,216
  unsigned short* kh     = (unsigned short*)(ws + 67108864);   // 16,777,216
  unsigned short* vhT    = (unsigned short*)(ws + 83886080);   // 16,777,216  [n*h][64][1024]
  unsigned short* ctx    = (unsigned short*)(ws + 100663296);  // 16,777,216
  float*          x1     = (float*)(ws + 117440512);           // 33,554,432
  unsigned short* t1     = qh;  // [8192][4096] bf16, aliases qh..ctx (dead by FFN)

  transpose_w<<<dim3(3072/32, 1024/32), 256, 0, stream>>>(Wqkv, Wqkv_t, 1024, 3072);
  transpose_w<<<dim3(1024/32, 1024/32), 256, 0, stream>>>(Wo,   Wo_t,   1024, 1024);
  transpose_w<<<dim3(4096/32, 1024/32), 256, 0, stream>>>(W1,   W1t,    1024, 4096);
  transpose_w<<<dim3(4096/32, 1024/32), 256, 0, stream>>>(W2,   W2t,    1024, 4096);
  transpose_w<<<dim3(1024/32, 4096/32), 256, 0, stream>>>(W3,   W3t,    4096, 1024);

  ln_kernel<<<MROWS, 256, 0, stream>>>(fin, vis, txt, aud, ln1g, ln1b, h);

  {  // QKV: M=8192, N=3072 -> 64x24 = 1536 blocks
    GemmP p{};
    p.A = h; p.Bt = Wqkv_t; p.K = 1024; p.N = 3072; p.bias = bqkv;
    p.oq = qh; p.ok = kh; p.ov = vhT;
    gemm_bn128<0><<<1536, 256, 0, stream>>>(p);
  }

  attn_kernel<<<2048, 256, 0, stream>>>(qh, kh, vhT, ctx);

  {  // proj + residual: N=1024 -> 512 blocks
    GemmP p{};
    p.A = ctx; p.Bt = Wo_t; p.K = 1024; p.N = 1024; p.bias = bo;
    p.r0 = fin; p.r1 = vis; p.r2 = txt; p.r3 = aud;
    p.of = x1;
    gemm_bn128<1><<<512, 256, 0, stream>>>(p);
  }

  ln_kernel<<<MROWS, 256, 0, stream>>>(x1, x1 + (size_t)2048 * 1024, x1 + (size_t)4096 * 1024,
                                       x1 + (size_t)6144 * 1024, ln2g, ln2b, h);

  // fused FFN up: silu(h@W1+b1)*(h@W2+b2) -> t1; 32x32 = 1024 blocks
  gemm_ffn<<<1024, 512, 0, stream>>>(h, W1t, W2t, b1, b2, t1);

  {  // FFN down + residual: N=1024, K=4096 -> 512 blocks
    GemmP p{};
    p.A = t1; p.Bt = W3t; p.K = HIDDIM; p.N = 1024; p.bias = b3;
    p.r0 = x1;
    p.of = (float*)d_out;
    gemm_bn128<4><<<512, 256, 0, stream>>>(p);
  }

  (void)in_sizes; (void)n_in; (void)out_size; (void)ws_size;
}

// Round 15
// 381.612 us; speedup vs baseline: 1.0317x; 1.0317x over previous
//
#include <hip/hip_runtime.h>

#define S_LEN  1024
#define DMODEL 1024
#define NHEAD  16
#define DHEAD  64
#define MROWS  8192   // 8 sequences * 1024
#define HIDDIM 4096
#define WINR   128

typedef __attribute__((ext_vector_type(8))) short bf16x8;
typedef __attribute__((ext_vector_type(4))) float f32x4;

__device__ __forceinline__ float bf2f(unsigned short u){ return __uint_as_float(((unsigned)u) << 16); }
__device__ __forceinline__ unsigned short f2bf(float f){
  unsigned u = __float_as_uint(f);
  u += 0x7FFFu + ((u >> 16) & 1u);
  return (unsigned short)(u >> 16);
}

// async global->LDS, 16 B per lane; lds dest is wave-uniform base (lane-linear fill)
__device__ __forceinline__ void gload_lds16(const unsigned short* g, unsigned short* l){
  __builtin_amdgcn_global_load_lds((const __attribute__((address_space(1))) unsigned int*)g,
                                   (__attribute__((address_space(3))) unsigned int*)l, 16, 0, 0);
}

// ---------------- weight transpose: in f32 [R][C] -> out bf16 [C][R] ----------------
__global__ __launch_bounds__(256) void transpose_w(const float* __restrict__ in,
                                                   unsigned short* __restrict__ out,
                                                   int R, int C){
  __shared__ float tile[32][33];
  const int c0 = blockIdx.x * 32;
  const int r0 = blockIdx.y * 32;
  const int tx = threadIdx.x & 31;
  const int ty = threadIdx.x >> 5;   // 0..7
  #pragma unroll
  for (int i = 0; i < 32; i += 8)
    tile[ty + i][tx] = in[(size_t)(r0 + ty + i) * C + c0 + tx];
  __syncthreads();
  #pragma unroll
  for (int i = 0; i < 32; i += 8)
    out[(size_t)(c0 + ty + i) * R + r0 + tx] = f2bf(tile[tx][ty + i]);
}

// ---------------- LayerNorm: row per block, 4 source pointers (2048 rows each) -------
__global__ __launch_bounds__(256) void ln_kernel(const float* __restrict__ s0, const float* __restrict__ s1,
                                                 const float* __restrict__ s2, const float* __restrict__ s3,
                                                 const float* __restrict__ g, const float* __restrict__ b,
                                                 unsigned short* __restrict__ out){
  const int row = blockIdx.x;
  const int t = threadIdx.x;
  const float* src = (row < 2048) ? s0 : (row < 4096) ? s1 : (row < 6144) ? s2 : s3;
  const float* x = src + (size_t)(row & 2047) * DMODEL;
  float4 v = *(const float4*)&x[t * 4];
  float sum  = v.x + v.y + v.z + v.w;
  float ssum = v.x*v.x + v.y*v.y + v.z*v.z + v.w*v.w;
  #pragma unroll
  for (int o = 32; o > 0; o >>= 1){
    sum  += __shfl_down(sum, o);
    ssum += __shfl_down(ssum, o);
  }
  __shared__ float red[8];
  if ((t & 63) == 0){ red[t >> 6] = sum; red[4 + (t >> 6)] = ssum; }
  __syncthreads();
  sum  = red[0] + red[1] + red[2] + red[3];
  ssum = red[4] + red[5] + red[6] + red[7];
  const float mu  = sum * (1.f / DMODEL);
  const float var = ssum * (1.f / DMODEL) - mu * mu;
  const float rs  = rsqrtf(var + 1e-5f);
  float4 gg = *(const float4*)&g[t * 4];
  float4 bb = *(const float4*)&b[t * 4];
  ushort4 o;
  o.x = f2bf((v.x - mu) * rs * gg.x + bb.x);
  o.y = f2bf((v.y - mu) * rs * gg.y + bb.y);
  o.z = f2bf((v.z - mu) * rs * gg.z + bb.z);
  o.w = f2bf((v.w - mu) * rs * gg.w + bb.w);
  *(ushort4*)&out[(size_t)row * DMODEL + t * 4] = o;
}

// ---------------- banded flash attention, MFMA 16x16x32, swapped QK^T ----------------
__global__ __launch_bounds__(256) void attn_kernel(const unsigned short* __restrict__ qh,
                                                   const unsigned short* __restrict__ kh,
                                                   const unsigned short* __restrict__ vt,
                                                   unsigned short* __restrict__ ctx){
  __shared__ unsigned short Ks[64 * 64];      // [key][d]  (d XOR-swizzled by key&7)
  __shared__ unsigned short Vs[64 * 64];      // [d][key]  (key XOR-swizzled by d&7)
  __shared__ unsigned short Ps[4][16 * 64];   // per-wave P [q][key] (key XOR by q&7)
  const int bx = blockIdx.x;
  const int qt = bx & 15, hd = (bx >> 4) & 15, n = bx >> 8;
  const int q0 = qt * 64;
  const int tid = threadIdx.x, lane = tid & 63, w = tid >> 6;
  const int hi = lane >> 4, lo = lane & 15;
  const size_t headoff = (size_t)(n * NHEAD + hd) * S_LEN * DHEAD;
  const unsigned short* kb = kh + headoff;
  const unsigned short* vb = vt + headoff;    // [64 d][1024 s]

  const int qg = q0 + w * 16 + lo;
  bf16x8 bq0 = *(const bf16x8*)(qh + headoff + (size_t)qg * DHEAD + hi * 8);
  bf16x8 bq1 = *(const bf16x8*)(qh + headoff + (size_t)qg * DHEAD + 32 + hi * 8);

  f32x4 oa[4];
  const f32x4 zero = {0.f, 0.f, 0.f, 0.f};
  #pragma unroll
  for (int dj = 0; dj < 4; dj++) oa[dj] = zero;
  float m = -20.f, lsum = 0.f;

  int t_first = q0 - WINR; if (t_first < 0) t_first = 0;
  int t_last  = q0 + 63 + WINR; if (t_last > S_LEN - 1) t_last = S_LEN - 1;

  const int sk = ((lane & 7) ^ (lane >> 3)) * 8;
  const int px = (lo & 7) * 8;

  for (int tb = t_first; tb <= t_last; tb += 64){
    __syncthreads();
    #pragma unroll
    for (int p = 0; p < 2; p++){
      const int r = w * 16 + p * 8 + (lane >> 3);
      gload_lds16(kb + (size_t)(tb + r) * DHEAD + sk, Ks + (w * 16 + p * 8) * 64);
      gload_lds16(vb + (size_t)r * S_LEN + tb + sk, Vs + (w * 16 + p * 8) * 64);
    }
    __syncthreads();

    f32x4 sc[4];
    #pragma unroll
    for (int j = 0; j < 4; j++){
      const int row = j * 16 + lo;
      bf16x8 ak0 = *(const bf16x8*)&Ks[row * 64 + ((hi * 8) ^ px)];
      bf16x8 ak1 = *(const bf16x8*)&Ks[row * 64 + ((32 + hi * 8) ^ px)];
      sc[j] = __builtin_amdgcn_mfma_f32_16x16x32_bf16(ak0, bq0, zero, 0, 0, 0);
      sc[j] = __builtin_amdgcn_mfma_f32_16x16x32_bf16(ak1, bq1, sc[j], 0, 0, 0);
    }

    float mloc = -1e30f;
    #pragma unroll
    for (int j = 0; j < 4; j++)
      #pragma unroll
      for (int r = 0; r < 4; r++){
        const int key = tb + j * 16 + hi * 4 + r;
        float s = sc[j][r] * 0.125f;
        s = ((unsigned)(key - qg + WINR) <= 2u * WINR) ? s : -1e9f;
        sc[j][r] = s;
        mloc = fmaxf(mloc, s);
      }
    mloc = fmaxf(mloc, __shfl_xor(mloc, 16));
    mloc = fmaxf(mloc, __shfl_xor(mloc, 32));
    const float nm = fmaxf(m, mloc);
    const float scale = __expf(m - nm);
    m = nm;
    float psum = 0.f;
    #pragma unroll
    for (int j = 0; j < 4; j++){
      float p0 = __expf(sc[j][0] - nm), p1 = __expf(sc[j][1] - nm);
      float p2 = __expf(sc[j][2] - nm), p3 = __expf(sc[j][3] - nm);
      psum += (p0 + p1) + (p2 + p3);
      ushort4 pw = { f2bf(p0), f2bf(p1), f2bf(p2), f2bf(p3) };
      *(ushort4*)&Ps[w][lo * 64 + ((hi * 4 + 16 * j) ^ px)] = pw;
    }
    psum += __shfl_xor(psum, 16);
    psum += __shfl_xor(psum, 32);
    lsum = lsum * scale + psum;

    float scr[4];
    #pragma unroll
    for (int r = 0; r < 4; r++) scr[r] = __shfl(scale, (lane & 48) + hi * 4 + r);
    #pragma unroll
    for (int dj = 0; dj < 4; dj++)
      #pragma unroll
      for (int r = 0; r < 4; r++) oa[dj][r] *= scr[r];

    bf16x8 pa0 = *(const bf16x8*)&Ps[w][lo * 64 + ((hi * 8) ^ px)];
    bf16x8 pa1 = *(const bf16x8*)&Ps[w][lo * 64 + ((32 + hi * 8) ^ px)];
    #pragma unroll
    for (int dj = 0; dj < 4; dj++){
      const int dr = dj * 16 + lo;
      bf16x8 bv0 = *(const bf16x8*)&Vs[dr * 64 + ((hi * 8) ^ px)];
      bf16x8 bv1 = *(const bf16x8*)&Vs[dr * 64 + ((32 + hi * 8) ^ px)];
      oa[dj] = __builtin_amdgcn_mfma_f32_16x16x32_bf16(pa0, bv0, oa[dj], 0, 0, 0);
      oa[dj] = __builtin_amdgcn_mfma_f32_16x16x32_bf16(pa1, bv1, oa[dj], 0, 0, 0);
    }
  }

  const float inv = 1.f / lsum;
  float invr[4];
  #pragma unroll
  for (int r = 0; r < 4; r++) invr[r] = __shfl(inv, (lane & 48) + hi * 4 + r);
  #pragma unroll
  for (int dj = 0; dj < 4; dj++)
    #pragma unroll
    for (int r = 0; r < 4; r++){
      const int srow = q0 + w * 16 + hi * 4 + r;
      ctx[((size_t)(n * S_LEN + srow)) * DMODEL + hd * DHEAD + dj * 16 + lo] =
          f2bf(oa[dj][r] * invr[r]);
    }
}

// ============ 128x128 bf16 MFMA GEMM, single-buffer 32 KB (round-13 proven) =========
struct GemmP {
  const unsigned short* A;
  const unsigned short* Bt;
  int K;
  int N;
  const float* bias;
  const float* r0; const float* r1; const float* r2; const float* r3;
  unsigned short* oq; unsigned short* ok; unsigned short* ov;   // qkv (ov = V^T)
  float* of;
};

// MODE 0: qkv head scatter (LDS-staged, V transposed)
// MODE 1: +bias +residual(sel by row) -> f32 direct float4
// MODE 4: +bias +r0 -> f32 direct float4
template<int MODE>
__global__ __launch_bounds__(256, 2) void gemm_bn128(GemmP p){
  __shared__ unsigned short ldsA[128 * 64];   // 16 KB
  __shared__ unsigned short ldsB[128 * 64];   // 16 KB
  const int tid  = threadIdx.x;
  const int lane = tid & 63;
  const int w    = tid >> 6;                // 0..3
  const int lo   = lane & 15, hi = lane >> 4;
  const int l3   = lane >> 3;
  const int sk   = ((lane & 7) ^ l3) * 8;   // pre-swizzled source k offset (elems)
  const int wm   = (w >> 1) * 64;           // 2M x 2N waves
  const int wn   = (w & 1) * 64;
  const int K    = p.K;

  const int nwg = gridDim.x;
  const int cpx = nwg >> 3;
  const int bsw = ((int)blockIdx.x & 7) * cpx + ((int)blockIdx.x >> 3);
  const int ntn = p.N >> 7;
  const int m0  = (bsw / ntn) * 128;
  const int n0  = (bsw % ntn) * 128;

  f32x4 acc[4][4];
  const f32x4 zero = {0.f, 0.f, 0.f, 0.f};
  #pragma unroll
  for (int i = 0; i < 4; i++)
    #pragma unroll
    for (int j = 0; j < 4; j++) acc[i][j] = zero;

  const int NT = K >> 6;
  for (int T = 0; T < NT; T++){
    const int kb = T * 64;
    __syncthreads();             // prev-tile LDS reads done before overwrite
    #pragma unroll
    for (int c = 0; c < 4; c++){
      const int r0 = w * 32 + c * 8;        // 4 waves x 8 rows x 4 calls = 128 rows
      gload_lds16(p.A  + (size_t)(m0 + r0 + l3) * K + kb + sk, &ldsA[r0 * 64]);
      gload_lds16(p.Bt + (size_t)(n0 + r0 + l3) * K + kb + sk, &ldsB[r0 * 64]);
    }
    __syncthreads();             // drains vmcnt: this tile's stage visible to all

    #pragma unroll
    for (int kk = 0; kk < 2; kk++){
      bf16x8 af[4], bfr[4];
      #pragma unroll
      for (int i = 0; i < 4; i++){
        const int R = wm + i * 16 + lo;
        af[i] = *(const bf16x8*)&ldsA[R * 64 + (((kk * 4 + hi) ^ (R & 7)) * 8)];
      }
      #pragma unroll
      for (int j = 0; j < 4; j++){
        const int R = wn + j * 16 + lo;
        bfr[j] = *(const bf16x8*)&ldsB[R * 64 + (((kk * 4 + hi) ^ (R & 7)) * 8)];
      }
      #pragma unroll
      for (int i = 0; i < 4; i++)
        #pragma unroll
        for (int j = 0; j < 4; j++)
          acc[i][j] = __builtin_amdgcn_mfma_f32_16x16x32_bf16(bfr[j], af[i], acc[i][j], 0, 0, 0);
    }
  }

  if constexpr (MODE == 1 || MODE == 4){
    // direct coalesced f32: thread stores float4 (4 adjacent cols, one row)
    const float* rs = p.r0;
    if constexpr (MODE == 1){
      const int rblk = m0 + wm;   // uniform per wave, never straddles 2048
      rs = (rblk < 2048) ? p.r0 : (rblk < 4096) ? p.r1 : (rblk < 6144) ? p.r2 : p.r3;
    }
    #pragma unroll
    for (int i = 0; i < 4; i++){
      const int row = m0 + wm + i * 16 + lo;
      #pragma unroll
      for (int j = 0; j < 4; j++){
        const int cb = n0 + wn + j * 16 + hi * 4;
        float4 b4 = *(const float4*)&p.bias[cb];
        float4 r4;
        if constexpr (MODE == 1) r4 = *(const float4*)&rs[(size_t)(row & 2047) * DMODEL + cb];
        else                     r4 = *(const float4*)&rs[(size_t)row * DMODEL + cb];
        float4 v;
        v.x = acc[i][j][0] + b4.x + r4.x;
        v.y = acc[i][j][1] + b4.y + r4.y;
        v.z = acc[i][j][2] + b4.z + r4.z;
        v.w = acc[i][j][3] + b4.w + r4.w;
        *(float4*)&p.of[(size_t)row * DMODEL + cb] = v;
      }
    }
  } else {
    // MODE 0: LDS-staged coalesced qkv scatter (per-wave 8 KB slice spanning ldsA+ldsB)
    __syncthreads();                                  // all K-loop LDS reads done
    unsigned short* sl = &ldsA[0] + w * 4096;
    const int nseq = (m0 + wm) >> 10;                 // uniform per wave
    const int sof  = (m0 + wm) & 1023;
    const bool isV = (n0 >> 10) == 2;
    if (!isV){
      // stage [s 64][c 64], 16B-chunk XOR by row&7
      #pragma unroll
      for (int i = 0; i < 4; i++){
        const int row = i * 16 + lo;
        #pragma unroll
        for (int j = 0; j < 4; j++){
          const int c  = j * 16 + hi * 4;
          const int cb = n0 + wn + c;
          float4 b4 = *(const float4*)&p.bias[cb];
          ushort4 o = { f2bf(acc[i][j][0] + b4.x), f2bf(acc[i][j][1] + b4.y),
                        f2bf(acc[i][j][2] + b4.z), f2bf(acc[i][j][3] + b4.w) };
          *(ushort4*)&sl[row * 64 + (((c >> 3) ^ (row & 7)) * 8) + (c & 7)] = o;
        }
      }
      asm volatile("s_waitcnt lgkmcnt(0)" ::: "memory");
      __builtin_amdgcn_sched_barrier(0);
      #pragma unroll
      for (int rep = 0; rep < 8; rep++){
        const int row = rep * 8 + l3;
        const int ch  = lane & 7;
        bf16x8 val = *(const bf16x8*)&sl[row * 64 + ((ch ^ (row & 7)) * 8)];
        const int cg = n0 + wn + ch * 8;
        const int hh = (cg & 1023) >> 6, d0 = cg & 63;
        unsigned short* dst = (cg >> 10) ? p.ok : p.oq;
        *(bf16x8*)&dst[((size_t)((nseq * NHEAD + hh) * S_LEN) + sof + row) * DHEAD + d0] = val;
      }
    } else {
      // V: stage transposed [d 64][s 64], 16B-chunk XOR by d&7
      #pragma unroll
      for (int i = 0; i < 4; i++){
        const int s = i * 16 + lo;
        #pragma unroll
        for (int j = 0; j < 4; j++){
          const int cb = n0 + wn + j * 16 + hi * 4;
          float4 b4 = *(const float4*)&p.bias[cb];
          #pragma unroll
          for (int r = 0; r < 4; r++){
            const int d = j * 16 + hi * 4 + r;
            const float bv = (r == 0) ? b4.x : (r == 1) ? b4.y : (r == 2) ? b4.z : b4.w;
            sl[d * 64 + (((s >> 3) ^ (d & 7)) * 8) + (s & 7)] = f2bf(acc[i][j][r] + bv);
          }
        }
      }
      asm volatile("s_waitcnt lgkmcnt(0)" ::: "memory");
      __builtin_amdgcn_sched_barrier(0);
      #pragma unroll
      for (int rep = 0; rep < 8; rep++){
        const int d  = rep * 8 + l3;
        const int ch = lane & 7;
        bf16x8 val = *(const bf16x8*)&sl[d * 64 + ((ch ^ (d & 7)) * 8)];
        const int cg = n0 + wn + d;
        const int hh = (cg & 1023) >> 6, dd = cg & 63;
        *(bf16x8*)&p.ov[((size_t)((nseq * NHEAD + hh) * DHEAD) + dd) * S_LEN + sof + ch * 8] = val;
      }
    }
  }
}

// ============ fused SwiGLU FFN-up: silu(A@W1^T+b1) * (A@W2^T+b2) -> bf16 =============
// Round-13 proven optimum: BM=128, BN=128 per GEMM, 256 threads (2Mx2N waves),
// single-buffer 48 KB LDS, classic 2-syncthreads K-loop, (256,2) -> VGPR 112, no spill.
__global__ __launch_bounds__(256, 2) void gemm_ffn(const unsigned short* __restrict__ A,
                                                   const unsigned short* __restrict__ B1t,
                                                   const unsigned short* __restrict__ B2t,
                                                   const float* __restrict__ b1,
                                                   const float* __restrict__ b2,
                                                   unsigned short* __restrict__ out){
  __shared__ unsigned short ldsA[128 * 64];    // 16 KB
  __shared__ unsigned short ldsB1[128 * 64];   // 16 KB
  __shared__ unsigned short ldsB2[128 * 64];   // 16 KB
  const int tid  = threadIdx.x;
  const int lane = tid & 63;
  const int w    = tid >> 6;                // 0..3
  const int lo   = lane & 15, hi = lane >> 4;
  const int l3   = lane >> 3;
  const int sk   = ((lane & 7) ^ l3) * 8;
  const int wm   = (w >> 1) * 64;
  const int wn   = (w & 1) * 64;

  const int nwg = gridDim.x;
  const int cpx = nwg >> 3;
  const int bsw = ((int)blockIdx.x & 7) * cpx + ((int)blockIdx.x >> 3);
  const int m0  = (bsw >> 5) * 128;     // ntn = 4096/128 = 32
  const int n0  = (bsw & 31) * 128;

  f32x4 a1[4][4], a2[4][4];
  const f32x4 zero = {0.f, 0.f, 0.f, 0.f};
  #pragma unroll
  for (int i = 0; i < 4; i++)
    #pragma unroll
    for (int j = 0; j < 4; j++){ a1[i][j] = zero; a2[i][j] = zero; }

  const int NT = DMODEL >> 6;    // 16
  for (int T = 0; T < NT; T++){
    const int kb = T * 64;
    __syncthreads();             // prev-tile LDS reads done before overwrite
    #pragma unroll
    for (int c = 0; c < 4; c++){
      const int r0 = w * 32 + c * 8;
      gload_lds16(A   + (size_t)(m0 + r0 + l3) * DMODEL + kb + sk, &ldsA[r0 * 64]);
      gload_lds16(B1t + (size_t)(n0 + r0 + l3) * DMODEL + kb + sk, &ldsB1[r0 * 64]);
      gload_lds16(B2t + (size_t)(n0 + r0 + l3) * DMODEL + kb + sk, &ldsB2[r0 * 64]);
    }
    __syncthreads();             // drains vmcnt: this tile's stage visible to all

    #pragma unroll
    for (int kk = 0; kk < 2; kk++){
      bf16x8 af[4], bf1[4], bf2[4];
      #pragma unroll
      for (int i = 0; i < 4; i++){
        const int R = wm + i * 16 + lo;
        af[i] = *(const bf16x8*)&ldsA[R * 64 + (((kk * 4 + hi) ^ (R & 7)) * 8)];
      }
      #pragma unroll
      for (int j = 0; j < 4; j++){
        const int R = wn + j * 16 + lo;
        const int off = R * 64 + (((kk * 4 + hi) ^ (R & 7)) * 8);
        bf1[j] = *(const bf16x8*)&ldsB1[off];
        bf2[j] = *(const bf16x8*)&ldsB2[off];
      }
      #pragma unroll
      for (int i = 0; i < 4; i++)
        #pragma unroll
        for (int j = 0; j < 4; j++){
          a1[i][j] = __builtin_amdgcn_mfma_f32_16x16x32_bf16(bf1[j], af[i], a1[i][j], 0, 0, 0);
          a2[i][j] = __builtin_amdgcn_mfma_f32_16x16x32_bf16(bf2[j], af[i], a2[i][j], 0, 0, 0);
        }
    }
  }

  // fused epilogue: LDS-staged coalesced bf16 (per-wave 8 KB slice in ldsA+ldsB1)
  __syncthreads();
  unsigned short* sl = &ldsA[0] + w * 4096;
  #pragma unroll
  for (int i = 0; i < 4; i++){
    const int row = i * 16 + lo;
    #pragma unroll
    for (int j = 0; j < 4; j++){
      const int c  = j * 16 + hi * 4;
      const int cb = n0 + wn + c;
      float4 g1 = *(const float4*)&b1[cb];
      float4 g2 = *(const float4*)&b2[cb];
      float v1[4] = { a1[i][j][0] + g1.x, a1[i][j][1] + g1.y, a1[i][j][2] + g1.z, a1[i][j][3] + g1.w };
      float v2[4] = { a2[i][j][0] + g2.x, a2[i][j][1] + g2.y, a2[i][j][2] + g2.z, a2[i][j][3] + g2.w };
      ushort4 o;
      o.x = f2bf(v1[0] / (1.f + __expf(-v1[0])) * v2[0]);
      o.y = f2bf(v1[1] / (1.f + __expf(-v1[1])) * v2[1]);
      o.z = f2bf(v1[2] / (1.f + __expf(-v1[2])) * v2[2]);
      o.w = f2bf(v1[3] / (1.f + __expf(-v1[3])) * v2[3]);
      *(ushort4*)&sl[row * 64 + (((c >> 3) ^ (row & 7)) * 8) + (c & 7)] = o;
    }
  }
  asm volatile("s_waitcnt lgkmcnt(0)" ::: "memory");
  __builtin_amdgcn_sched_barrier(0);
  #pragma unroll
  for (int rep = 0; rep < 8; rep++){
    const int row = rep * 8 + l3;
    const int ch  = lane & 7;
    bf16x8 val = *(const bf16x8*)&sl[row * 64 + ((ch ^ (row & 7)) * 8)];
    *(bf16x8*)&out[(size_t)(m0 + wm + row) * HIDDIM + n0 + wn + ch * 8] = val;
  }
}

// ------------------------------------------------------------------------------------
extern "C" void kernel_launch(void* const* d_in, const int* in_sizes, int n_in,
                              void* d_out, int out_size, void* d_ws, size_t ws_size,
                              hipStream_t stream){
  const float* fin  = (const float*)d_in[0];
  const float* vis  = (const float*)d_in[1];
  const float* txt  = (const float*)d_in[2];
  const float* aud  = (const float*)d_in[3];
  const float* ln1g = (const float*)d_in[4];
  const float* ln1b = (const float*)d_in[5];
  const float* Wqkv = (const float*)d_in[6];
  const float* bqkv = (const float*)d_in[7];
  const float* Wo   = (const float*)d_in[8];
  const float* bo   = (const float*)d_in[9];
  const float* ln2g = (const float*)d_in[10];
  const float* ln2b = (const float*)d_in[11];
  const float* W1   = (const float*)d_in[12];
  const float* b1   = (const float*)d_in[13];
  const float* W2   = (const float*)d_in[14];
  const float* b2   = (const float*)d_in[15];
  const float* W3   = (const float*)d_in[16];
  const float* b3   = (const float*)d_in[17];

  char* ws = (char*)d_ws;
  unsigned short* Wqkv_t = (unsigned short*)(ws + 0);          //  6,291,456
  unsigned short* Wo_t   = (unsigned short*)(ws + 6291456);    //  2,097,152
  unsigned short* W1t    = (unsigned short*)(ws + 8388608);    //  8,388,608
  unsigned short* W2t    = (unsigned short*)(ws + 16777216);   //  8,388,608
  unsigned short* W3t    = (unsigned short*)(ws + 25165824);   //  8,388,608
  unsigned short* h      = (unsigned short*)(ws + 33554432);   // 16,777,216
  unsigned short* qh     = (unsigned short*)(ws + 50331648);   // 16,777,216
  unsigned short* kh     = (unsigned short*)(ws + 67108864);   // 16,777,216
  unsigned short* vhT    = (unsigned short*)(ws + 83886080);   // 16,777,216  [n*h][64][1024]
  unsigned short* ctx    = (unsigned short*)(ws + 100663296);  // 16,777,216
  float*          x1     = (float*)(ws + 117440512);           // 33,554,432
  unsigned short* t1     = qh;  // [8192][4096] bf16, aliases qh..ctx (dead by FFN)

  transpose_w<<<dim3(3072/32, 1024/32), 256, 0, stream>>>(Wqkv, Wqkv_t, 1024, 3072);
  transpose_w<<<dim3(1024/32, 1024/32), 256, 0, stream>>>(Wo,   Wo_t,   1024, 1024);
  transpose_w<<<dim3(4096/32, 1024/32), 256, 0, stream>>>(W1,   W1t,    1024, 4096);
  transpose_w<<<dim3(4096/32, 1024/32), 256, 0, stream>>>(W2,   W2t,    1024, 4096);
  transpose_w<<<dim3(1024/32, 4096/32), 256, 0, stream>>>(W3,   W3t,    4096, 1024);

  ln_kernel<<<MROWS, 256, 0, stream>>>(fin, vis, txt, aud, ln1g, ln1b, h);

  {  // QKV: M=8192, N=3072 -> 64x24 = 1536 blocks
    GemmP p{};
    p.A = h; p.Bt = Wqkv_t; p.K = 1024; p.N = 3072; p.bias = bqkv;
    p.oq = qh; p.ok = kh; p.ov = vhT;
    gemm_bn128<0><<<1536, 256, 0, stream>>>(p);
  }

  attn_kernel<<<2048, 256, 0, stream>>>(qh, kh, vhT, ctx);

  {  // proj + residual: N=1024 -> 512 blocks
    GemmP p{};
    p.A = ctx; p.Bt = Wo_t; p.K = 1024; p.N = 1024; p.bias = bo;
    p.r0 = fin; p.r1 = vis; p.r2 = txt; p.r3 = aud;
    p.of = x1;
    gemm_bn128<1><<<512, 256, 0, stream>>>(p);
  }

  ln_kernel<<<MROWS, 256, 0, stream>>>(x1, x1 + (size_t)2048 * 1024, x1 + (size_t)4096 * 1024,
                                       x1 + (size_t)6144 * 1024, ln2g, ln2b, h);

  // fused FFN up: silu(h@W1+b1)*(h@W2+b2) -> t1; 64x32 = 2048 blocks
  gemm_ffn<<<2048, 256, 0, stream>>>(h, W1t, W2t, b1, b2, t1);

  {  // FFN down + residual: N=1024, K=4096 -> 512 blocks
    GemmP p{};
    p.A = t1; p.Bt = W3t; p.K = HIDDIM; p.N = 1024; p.bias = b3;
    p.r0 = x1;
    p.of = (float*)d_out;
    gemm_bn128<4><<<512, 256, 0, stream>>>(p);
  }

  (void)in_sizes; (void)n_in; (void)out_size; (void)ws_size;
}

// Round 16
// 367.741 us; speedup vs baseline: 1.0707x; 1.0377x over previous
//
#include <hip/hip_runtime.h>

#define S_LEN  1024
#define DMODEL 1024
#define NHEAD  16
#define DHEAD  64
#define MROWS  8192   // 8 sequences * 1024
#define HIDDIM 4096
#define WINR   128

typedef __attribute__((ext_vector_type(8))) short bf16x8;
typedef __attribute__((ext_vector_type(4))) float f32x4;

__device__ __forceinline__ float bf2f(unsigned short u){ return __uint_as_float(((unsigned)u) << 16); }
__device__ __forceinline__ unsigned short f2bf(float f){
  unsigned u = __float_as_uint(f);
  u += 0x7FFFu + ((u >> 16) & 1u);
  return (unsigned short)(u >> 16);
}

// async global->LDS, 16 B per lane; lds dest is wave-uniform base (lane-linear fill)
__device__ __forceinline__ void gload_lds16(const unsigned short* g, unsigned short* l){
  __builtin_amdgcn_global_load_lds((const __attribute__((address_space(1))) unsigned int*)g,
                                   (__attribute__((address_space(3))) unsigned int*)l, 16, 0, 0);
}

// ---------------- weight transpose: in f32 [R][C] -> out bf16 [C][R] ----------------
__global__ __launch_bounds__(256) void transpose_w(const float* __restrict__ in,
                                                   unsigned short* __restrict__ out,
                                                   int R, int C){
  __shared__ float tile[32][33];
  const int c0 = blockIdx.x * 32;
  const int r0 = blockIdx.y * 32;
  const int tx = threadIdx.x & 31;
  const int ty = threadIdx.x >> 5;   // 0..7
  #pragma unroll
  for (int i = 0; i < 32; i += 8)
    tile[ty + i][tx] = in[(size_t)(r0 + ty + i) * C + c0 + tx];
  __syncthreads();
  #pragma unroll
  for (int i = 0; i < 32; i += 8)
    out[(size_t)(c0 + ty + i) * R + r0 + tx] = f2bf(tile[tx][ty + i]);
}

// ---------------- LayerNorm: row per block, 4 source pointers (2048 rows each) -------
__global__ __launch_bounds__(256) void ln_kernel(const float* __restrict__ s0, const float* __restrict__ s1,
                                                 const float* __restrict__ s2, const float* __restrict__ s3,
                                                 const float* __restrict__ g, const float* __restrict__ b,
                                                 unsigned short* __restrict__ out){
  const int row = blockIdx.x;
  const int t = threadIdx.x;
  const float* src = (row < 2048) ? s0 : (row < 4096) ? s1 : (row < 6144) ? s2 : s3;
  const float* x = src + (size_t)(row & 2047) * DMODEL;
  float4 v = *(const float4*)&x[t * 4];
  float sum  = v.x + v.y + v.z + v.w;
  float ssum = v.x*v.x + v.y*v.y + v.z*v.z + v.w*v.w;
  #pragma unroll
  for (int o = 32; o > 0; o >>= 1){
    sum  += __shfl_down(sum, o);
    ssum += __shfl_down(ssum, o);
  }
  __shared__ float red[8];
  if ((t & 63) == 0){ red[t >> 6] = sum; red[4 + (t >> 6)] = ssum; }
  __syncthreads();
  sum  = red[0] + red[1] + red[2] + red[3];
  ssum = red[4] + red[5] + red[6] + red[7];
  const float mu  = sum * (1.f / DMODEL);
  const float var = ssum * (1.f / DMODEL) - mu * mu;
  const float rs  = rsqrtf(var + 1e-5f);
  float4 gg = *(const float4*)&g[t * 4];
  float4 bb = *(const float4*)&b[t * 4];
  ushort4 o;
  o.x = f2bf((v.x - mu) * rs * gg.x + bb.x);
  o.y = f2bf((v.y - mu) * rs * gg.y + bb.y);
  o.z = f2bf((v.z - mu) * rs * gg.z + bb.z);
  o.w = f2bf((v.w - mu) * rs * gg.w + bb.w);
  *(ushort4*)&out[(size_t)row * DMODEL + t * 4] = o;
}

// ---------------- banded flash attention, MFMA 16x16x32, swapped QK^T ----------------
__global__ __launch_bounds__(256) void attn_kernel(const unsigned short* __restrict__ qh,
                                                   const unsigned short* __restrict__ kh,
                                                   const unsigned short* __restrict__ vt,
                                                   unsigned short* __restrict__ ctx){
  __shared__ unsigned short Ks[64 * 64];      // [key][d]  (d XOR-swizzled by key&7)
  __shared__ unsigned short Vs[64 * 64];      // [d][key]  (key XOR-swizzled by d&7)
  __shared__ unsigned short Ps[4][16 * 64];   // per-wave P [q][key] (key XOR by q&7)
  const int bx = blockIdx.x;
  const int qt = bx & 15, hd = (bx >> 4) & 15, n = bx >> 8;
  const int q0 = qt * 64;
  const int tid = threadIdx.x, lane = tid & 63, w = tid >> 6;
  const int hi = lane >> 4, lo = lane & 15;
  const size_t headoff = (size_t)(n * NHEAD + hd) * S_LEN * DHEAD;
  const unsigned short* kb = kh + headoff;
  const unsigned short* vb = vt + headoff;    // [64 d][1024 s]

  const int qg = q0 + w * 16 + lo;
  bf16x8 bq0 = *(const bf16x8*)(qh + headoff + (size_t)qg * DHEAD + hi * 8);
  bf16x8 bq1 = *(const bf16x8*)(qh + headoff + (size_t)qg * DHEAD + 32 + hi * 8);

  f32x4 oa[4];
  const f32x4 zero = {0.f, 0.f, 0.f, 0.f};
  #pragma unroll
  for (int dj = 0; dj < 4; dj++) oa[dj] = zero;
  float m = -20.f, lsum = 0.f;

  int t_first = q0 - WINR; if (t_first < 0) t_first = 0;
  int t_last  = q0 + 63 + WINR; if (t_last > S_LEN - 1) t_last = S_LEN - 1;

  const int sk = ((lane & 7) ^ (lane >> 3)) * 8;
  const int px = (lo & 7) * 8;

  for (int tb = t_first; tb <= t_last; tb += 64){
    __syncthreads();
    #pragma unroll
    for (int p = 0; p < 2; p++){
      const int r = w * 16 + p * 8 + (lane >> 3);
      gload_lds16(kb + (size_t)(tb + r) * DHEAD + sk, Ks + (w * 16 + p * 8) * 64);
      gload_lds16(vb + (size_t)r * S_LEN + tb + sk, Vs + (w * 16 + p * 8) * 64);
    }
    __syncthreads();

    f32x4 sc[4];
    #pragma unroll
    for (int j = 0; j < 4; j++){
      const int row = j * 16 + lo;
      bf16x8 ak0 = *(const bf16x8*)&Ks[row * 64 + ((hi * 8) ^ px)];
      bf16x8 ak1 = *(const bf16x8*)&Ks[row * 64 + ((32 + hi * 8) ^ px)];
      sc[j] = __builtin_amdgcn_mfma_f32_16x16x32_bf16(ak0, bq0, zero, 0, 0, 0);
      sc[j] = __builtin_amdgcn_mfma_f32_16x16x32_bf16(ak1, bq1, sc[j], 0, 0, 0);
    }

    float mloc = -1e30f;
    #pragma unroll
    for (int j = 0; j < 4; j++)
      #pragma unroll
      for (int r = 0; r < 4; r++){
        const int key = tb + j * 16 + hi * 4 + r;
        float s = sc[j][r] * 0.125f;
        s = ((unsigned)(key - qg + WINR) <= 2u * WINR) ? s : -1e9f;
        sc[j][r] = s;
        mloc = fmaxf(mloc, s);
      }
    mloc = fmaxf(mloc, __shfl_xor(mloc, 16));
    mloc = fmaxf(mloc, __shfl_xor(mloc, 32));
    const float nm = fmaxf(m, mloc);
    const float scale = __expf(m - nm);
    m = nm;
    float psum = 0.f;
    #pragma unroll
    for (int j = 0; j < 4; j++){
      float p0 = __expf(sc[j][0] - nm), p1 = __expf(sc[j][1] - nm);
      float p2 = __expf(sc[j][2] - nm), p3 = __expf(sc[j][3] - nm);
      psum += (p0 + p1) + (p2 + p3);
      ushort4 pw = { f2bf(p0), f2bf(p1), f2bf(p2), f2bf(p3) };
      *(ushort4*)&Ps[w][lo * 64 + ((hi * 4 + 16 * j) ^ px)] = pw;
    }
    psum += __shfl_xor(psum, 16);
    psum += __shfl_xor(psum, 32);
    lsum = lsum * scale + psum;

    float scr[4];
    #pragma unroll
    for (int r = 0; r < 4; r++) scr[r] = __shfl(scale, (lane & 48) + hi * 4 + r);
    #pragma unroll
    for (int dj = 0; dj < 4; dj++)
      #pragma unroll
      for (int r = 0; r < 4; r++) oa[dj][r] *= scr[r];

    bf16x8 pa0 = *(const bf16x8*)&Ps[w][lo * 64 + ((hi * 8) ^ px)];
    bf16x8 pa1 = *(const bf16x8*)&Ps[w][lo * 64 + ((32 + hi * 8) ^ px)];
    #pragma unroll
    for (int dj = 0; dj < 4; dj++){
      const int dr = dj * 16 + lo;
      bf16x8 bv0 = *(const bf16x8*)&Vs[dr * 64 + ((hi * 8) ^ px)];
      bf16x8 bv1 = *(const bf16x8*)&Vs[dr * 64 + ((32 + hi * 8) ^ px)];
      oa[dj] = __builtin_amdgcn_mfma_f32_16x16x32_bf16(pa0, bv0, oa[dj], 0, 0, 0);
      oa[dj] = __builtin_amdgcn_mfma_f32_16x16x32_bf16(pa1, bv1, oa[dj], 0, 0, 0);
    }
  }

  const float inv = 1.f / lsum;
  float invr[4];
  #pragma unroll
  for (int r = 0; r < 4; r++) invr[r] = __shfl(inv, (lane & 48) + hi * 4 + r);
  #pragma unroll
  for (int dj = 0; dj < 4; dj++)
    #pragma unroll
    for (int r = 0; r < 4; r++){
      const int srow = q0 + w * 16 + hi * 4 + r;
      ctx[((size_t)(n * S_LEN + srow)) * DMODEL + hd * DHEAD + dj * 16 + lo] =
          f2bf(oa[dj][r] * invr[r]);
    }
}

// ============ 128x128 bf16 MFMA GEMM, single-buffer 32 KB (round-13 proven) =========
struct GemmP {
  const unsigned short* A;
  const unsigned short* Bt;
  int K;
  int N;
  const float* bias;
  const float* r0; const float* r1; const float* r2; const float* r3;
  unsigned short* oq; unsigned short* ok; unsigned short* ov;   // qkv (ov = V^T)
  float* of;
};

// MODE 0: qkv head scatter (LDS-staged, V transposed)
// MODE 1: +bias +residual(sel by row) -> f32 direct float4
// MODE 4: +bias +r0 -> f32 direct float4
template<int MODE>
__global__ __launch_bounds__(256, 2) void gemm_bn128(GemmP p){
  __shared__ unsigned short ldsA[128 * 64];   // 16 KB
  __shared__ unsigned short ldsB[128 * 64];   // 16 KB
  const int tid  = threadIdx.x;
  const int lane = tid & 63;
  const int w    = tid >> 6;                // 0..3
  const int lo   = lane & 15, hi = lane >> 4;
  const int l3   = lane >> 3;
  const int sk   = ((lane & 7) ^ l3) * 8;   // pre-swizzled source k offset (elems)
  const int wm   = (w >> 1) * 64;           // 2M x 2N waves
  const int wn   = (w & 1) * 64;
  const int K    = p.K;

  const int nwg = gridDim.x;
  const int cpx = nwg >> 3;
  const int bsw = ((int)blockIdx.x & 7) * cpx + ((int)blockIdx.x >> 3);
  const int ntn = p.N >> 7;
  const int m0  = (bsw / ntn) * 128;
  const int n0  = (bsw % ntn) * 128;

  f32x4 acc[4][4];
  const f32x4 zero = {0.f, 0.f, 0.f, 0.f};
  #pragma unroll
  for (int i = 0; i < 4; i++)
    #pragma unroll
    for (int j = 0; j < 4; j++) acc[i][j] = zero;

  const int NT = K >> 6;
  for (int T = 0; T < NT; T++){
    const int kb = T * 64;
    __syncthreads();             // prev-tile LDS reads done before overwrite
    #pragma unroll
    for (int c = 0; c < 4; c++){
      const int r0 = w * 32 + c * 8;        // 4 waves x 8 rows x 4 calls = 128 rows
      gload_lds16(p.A  + (size_t)(m0 + r0 + l3) * K + kb + sk, &ldsA[r0 * 64]);
      gload_lds16(p.Bt + (size_t)(n0 + r0 + l3) * K + kb + sk, &ldsB[r0 * 64]);
    }
    __syncthreads();             // drains vmcnt: this tile's stage visible to all

    #pragma unroll
    for (int kk = 0; kk < 2; kk++){
      bf16x8 af[4], bfr[4];
      #pragma unroll
      for (int i = 0; i < 4; i++){
        const int R = wm + i * 16 + lo;
        af[i] = *(const bf16x8*)&ldsA[R * 64 + (((kk * 4 + hi) ^ (R & 7)) * 8)];
      }
      #pragma unroll
      for (int j = 0; j < 4; j++){
        const int R = wn + j * 16 + lo;
        bfr[j] = *(const bf16x8*)&ldsB[R * 64 + (((kk * 4 + hi) ^ (R & 7)) * 8)];
      }
      #pragma unroll
      for (int i = 0; i < 4; i++)
        #pragma unroll
        for (int j = 0; j < 4; j++)
          acc[i][j] = __builtin_amdgcn_mfma_f32_16x16x32_bf16(bfr[j], af[i], acc[i][j], 0, 0, 0);
    }
  }

  if constexpr (MODE == 1 || MODE == 4){
    // direct coalesced f32: thread stores float4 (4 adjacent cols, one row)
    const float* rs = p.r0;
    if constexpr (MODE == 1){
      const int rblk = m0 + wm;   // uniform per wave, never straddles 2048
      rs = (rblk < 2048) ? p.r0 : (rblk < 4096) ? p.r1 : (rblk < 6144) ? p.r2 : p.r3;
    }
    #pragma unroll
    for (int i = 0; i < 4; i++){
      const int row = m0 + wm + i * 16 + lo;
      #pragma unroll
      for (int j = 0; j < 4; j++){
        const int cb = n0 + wn + j * 16 + hi * 4;
        float4 b4 = *(const float4*)&p.bias[cb];
        float4 r4;
        if constexpr (MODE == 1) r4 = *(const float4*)&rs[(size_t)(row & 2047) * DMODEL + cb];
        else                     r4 = *(const float4*)&rs[(size_t)row * DMODEL + cb];
        float4 v;
        v.x = acc[i][j][0] + b4.x + r4.x;
        v.y = acc[i][j][1] + b4.y + r4.y;
        v.z = acc[i][j][2] + b4.z + r4.z;
        v.w = acc[i][j][3] + b4.w + r4.w;
        *(float4*)&p.of[(size_t)row * DMODEL + cb] = v;
      }
    }
  } else {
    // MODE 0: LDS-staged coalesced qkv scatter (per-wave 8 KB slice spanning ldsA+ldsB)
    __syncthreads();                                  // all K-loop LDS reads done
    unsigned short* sl = &ldsA[0] + w * 4096;
    const int nseq = (m0 + wm) >> 10;                 // uniform per wave
    const int sof  = (m0 + wm) & 1023;
    const bool isV = (n0 >> 10) == 2;
    if (!isV){
      // stage [s 64][c 64], 16B-chunk XOR by row&7
      #pragma unroll
      for (int i = 0; i < 4; i++){
        const int row = i * 16 + lo;
        #pragma unroll
        for (int j = 0; j < 4; j++){
          const int c  = j * 16 + hi * 4;
          const int cb = n0 + wn + c;
          float4 b4 = *(const float4*)&p.bias[cb];
          ushort4 o = { f2bf(acc[i][j][0] + b4.x), f2bf(acc[i][j][1] + b4.y),
                        f2bf(acc[i][j][2] + b4.z), f2bf(acc[i][j][3] + b4.w) };
          *(ushort4*)&sl[row * 64 + (((c >> 3) ^ (row & 7)) * 8) + (c & 7)] = o;
        }
      }
      asm volatile("s_waitcnt lgkmcnt(0)" ::: "memory");
      __builtin_amdgcn_sched_barrier(0);
      #pragma unroll
      for (int rep = 0; rep < 8; rep++){
        const int row = rep * 8 + l3;
        const int ch  = lane & 7;
        bf16x8 val = *(const bf16x8*)&sl[row * 64 + ((ch ^ (row & 7)) * 8)];
        const int cg = n0 + wn + ch * 8;
        const int hh = (cg & 1023) >> 6, d0 = cg & 63;
        unsigned short* dst = (cg >> 10) ? p.ok : p.oq;
        *(bf16x8*)&dst[((size_t)((nseq * NHEAD + hh) * S_LEN) + sof + row) * DHEAD + d0] = val;
      }
    } else {
      // V: stage transposed [d 64][s 64], 16B-chunk XOR by d&7
      #pragma unroll
      for (int i = 0; i < 4; i++){
        const int s = i * 16 + lo;
        #pragma unroll
        for (int j = 0; j < 4; j++){
          const int cb = n0 + wn + j * 16 + hi * 4;
          float4 b4 = *(const float4*)&p.bias[cb];
          #pragma unroll
          for (int r = 0; r < 4; r++){
            const int d = j * 16 + hi * 4 + r;
            const float bv = (r == 0) ? b4.x : (r == 1) ? b4.y : (r == 2) ? b4.z : b4.w;
            sl[d * 64 + (((s >> 3) ^ (d & 7)) * 8) + (s & 7)] = f2bf(acc[i][j][r] + bv);
          }
        }
      }
      asm volatile("s_waitcnt lgkmcnt(0)" ::: "memory");
      __builtin_amdgcn_sched_barrier(0);
      #pragma unroll
      for (int rep = 0; rep < 8; rep++){
        const int d  = rep * 8 + l3;
        const int ch = lane & 7;
        bf16x8 val = *(const bf16x8*)&sl[d * 64 + ((ch ^ (d & 7)) * 8)];
        const int cg = n0 + wn + d;
        const int hh = (cg & 1023) >> 6, dd = cg & 63;
        *(bf16x8*)&p.ov[((size_t)((nseq * NHEAD + hh) * DHEAD) + dd) * S_LEN + sof + ch * 8] = val;
      }
    }
  }
}

// ============ fused SwiGLU FFN-up: silu(A@W1^T+b1) * (A@W2^T+b2) -> bf16 =============
// Round-13 proven body; ONLY the block->tile mapping changes: within each XCD's
// 256-block chunk (8 m x 32 n), traverse 4m x 4n SUPER-TILES (A 1MB + B 2MB < 4MB L2)
// n-fastest across super-cols -> B re-fetched 2x/XCD instead of 8x.
__global__ __launch_bounds__(256, 2) void gemm_ffn(const unsigned short* __restrict__ A,
                                                   const unsigned short* __restrict__ B1t,
                                                   const unsigned short* __restrict__ B2t,
                                                   const float* __restrict__ b1,
                                                   const float* __restrict__ b2,
                                                   unsigned short* __restrict__ out){
  __shared__ unsigned short ldsA[128 * 64];    // 16 KB
  __shared__ unsigned short ldsB1[128 * 64];   // 16 KB
  __shared__ unsigned short ldsB2[128 * 64];   // 16 KB
  const int tid  = threadIdx.x;
  const int lane = tid & 63;
  const int w    = tid >> 6;                // 0..3
  const int lo   = lane & 15, hi = lane >> 4;
  const int l3   = lane >> 3;
  const int sk   = ((lane & 7) ^ l3) * 8;
  const int wm   = (w >> 1) * 64;
  const int wn   = (w & 1) * 64;

  // XCD chunk (256 blocks = 8m x 32n) -> super-tiles 4m x 4n, n-fastest supers.
  // chunk-local bits: [7]=super-row, [6:4]=super-col, [3:2]=m-in-super, [1:0]=n-in-super
  const int xcd = (int)blockIdx.x & 7;
  const int c   = (int)blockIdx.x >> 3;     // 0..255 chunk-local
  const int mt  = xcd * 8 + ((c >> 7) & 1) * 4 + ((c >> 2) & 3);   // m-tile 0..63
  const int nt  = ((c >> 4) & 7) * 4 + (c & 3);                    // n-tile 0..31
  const int m0  = mt * 128;
  const int n0  = nt * 128;

  f32x4 a1[4][4], a2[4][4];
  const f32x4 zero = {0.f, 0.f, 0.f, 0.f};
  #pragma unroll
  for (int i = 0; i < 4; i++)
    #pragma unroll
    for (int j = 0; j < 4; j++){ a1[i][j] = zero; a2[i][j] = zero; }

  const int NT = DMODEL >> 6;    // 16
  for (int T = 0; T < NT; T++){
    const int kb = T * 64;
    __syncthreads();             // prev-tile LDS reads done before overwrite
    #pragma unroll
    for (int cc = 0; cc < 4; cc++){
      const int r0 = w * 32 + cc * 8;
      gload_lds16(A   + (size_t)(m0 + r0 + l3) * DMODEL + kb + sk, &ldsA[r0 * 64]);
      gload_lds16(B1t + (size_t)(n0 + r0 + l3) * DMODEL + kb + sk, &ldsB1[r0 * 64]);
      gload_lds16(B2t + (size_t)(n0 + r0 + l3) * DMODEL + kb + sk, &ldsB2[r0 * 64]);
    }
    __syncthreads();             // drains vmcnt: this tile's stage visible to all

    #pragma unroll
    for (int kk = 0; kk < 2; kk++){
      bf16x8 af[4], bf1[4], bf2[4];
      #pragma unroll
      for (int i = 0; i < 4; i++){
        const int R = wm + i * 16 + lo;
        af[i] = *(const bf16x8*)&ldsA[R * 64 + (((kk * 4 + hi) ^ (R & 7)) * 8)];
      }
      #pragma unroll
      for (int j = 0; j < 4; j++){
        const int R = wn + j * 16 + lo;
        const int off = R * 64 + (((kk * 4 + hi) ^ (R & 7)) * 8);
        bf1[j] = *(const bf16x8*)&ldsB1[off];
        bf2[j] = *(const bf16x8*)&ldsB2[off];
      }
      #pragma unroll
      for (int i = 0; i < 4; i++)
        #pragma unroll
        for (int j = 0; j < 4; j++){
          a1[i][j] = __builtin_amdgcn_mfma_f32_16x16x32_bf16(bf1[j], af[i], a1[i][j], 0, 0, 0);
          a2[i][j] = __builtin_amdgcn_mfma_f32_16x16x32_bf16(bf2[j], af[i], a2[i][j], 0, 0, 0);
        }
    }
  }

  // fused epilogue: LDS-staged coalesced bf16 (per-wave 8 KB slice in ldsA+ldsB1)
  __syncthreads();
  unsigned short* sl = &ldsA[0] + w * 4096;
  #pragma unroll
  for (int i = 0; i < 4; i++){
    const int row = i * 16 + lo;
    #pragma unroll
    for (int j = 0; j < 4; j++){
      const int cc = j * 16 + hi * 4;
      const int cb = n0 + wn + cc;
      float4 g1 = *(const float4*)&b1[cb];
      float4 g2 = *(const float4*)&b2[cb];
      float v1[4] = { a1[i][j][0] + g1.x, a1[i][j][1] + g1.y, a1[i][j][2] + g1.z, a1[i][j][3] + g1.w };
      float v2[4] = { a2[i][j][0] + g2.x, a2[i][j][1] + g2.y, a2[i][j][2] + g2.z, a2[i][j][3] + g2.w };
      ushort4 o;
      o.x = f2bf(v1[0] / (1.f + __expf(-v1[0])) * v2[0]);
      o.y = f2bf(v1[1] / (1.f + __expf(-v1[1])) * v2[1]);
      o.z = f2bf(v1[2] / (1.f + __expf(-v1[2])) * v2[2]);
      o.w = f2bf(v1[3] / (1.f + __expf(-v1[3])) * v2[3]);
      *(ushort4*)&sl[row * 64 + (((cc >> 3) ^ (row & 7)) * 8) + (cc & 7)] = o;
    }
  }
  asm volatile("s_waitcnt lgkmcnt(0)" ::: "memory");
  __builtin_amdgcn_sched_barrier(0);
  #pragma unroll
  for (int rep = 0; rep < 8; rep++){
    const int row = rep * 8 + l3;
    const int ch  = lane & 7;
    bf16x8 val = *(const bf16x8*)&sl[row * 64 + ((ch ^ (row & 7)) * 8)];
    *(bf16x8*)&out[(size_t)(m0 + wm + row) * HIDDIM + n0 + wn + ch * 8] = val;
  }
}

// ------------------------------------------------------------------------------------
extern "C" void kernel_launch(void* const* d_in, const int* in_sizes, int n_in,
                              void* d_out, int out_size, void* d_ws, size_t ws_size,
                              hipStream_t stream){
  const float* fin  = (const float*)d_in[0];
  const float* vis  = (const float*)d_in[1];
  const float* txt  = (const float*)d_in[2];
  const float* aud  = (const float*)d_in[3];
  const float* ln1g = (const float*)d_in[4];
  const float* ln1b = (const float*)d_in[5];
  const float* Wqkv = (const float*)d_in[6];
  const float* bqkv = (const float*)d_in[7];
  const float* Wo   = (const float*)d_in[8];
  const float* bo   = (const float*)d_in[9];
  const float* ln2g = (const float*)d_in[10];
  const float* ln2b = (const float*)d_in[11];
  const float* W1   = (const float*)d_in[12];
  const float* b1   = (const float*)d_in[13];
  const float* W2   = (const float*)d_in[14];
  const float* b2   = (const float*)d_in[15];
  const float* W3   = (const float*)d_in[16];
  const float* b3   = (const float*)d_in[17];

  char* ws = (char*)d_ws;
  unsigned short* Wqkv_t = (unsigned short*)(ws + 0);          //  6,291,456
  unsigned short* Wo_t   = (unsigned short*)(ws + 6291456);    //  2,097,152
  unsigned short* W1t    = (unsigned short*)(ws + 8388608);    //  8,388,608
  unsigned short* W2t    = (unsigned short*)(ws + 16777216);   //  8,388,608
  unsigned short* W3t    = (unsigned short*)(ws + 25165824);   //  8,388,608
  unsigned short* h      = (unsigned short*)(ws + 33554432);   // 16,777,216
  unsigned short* qh     = (unsigned short*)(ws + 50331648);   // 16,777,216
  unsigned short* kh     = (unsigned short*)(ws + 67108864);   // 16,777,216
  unsigned short* vhT    = (unsigned short*)(ws + 83886080);   // 16,777,216  [n*h][64][1024]
  unsigned short* ctx    = (unsigned short*)(ws + 100663296);  // 16,777,216
  float*          x1     = (float*)(ws + 117440512);           // 33,554,432
  unsigned short* t1     = qh;  // [8192][4096] bf16, aliases qh..ctx (dead by FFN)

  transpose_w<<<dim3(3072/32, 1024/32), 256, 0, stream>>>(Wqkv, Wqkv_t, 1024, 3072);
  transpose_w<<<dim3(1024/32, 1024/32), 256, 0, stream>>>(Wo,   Wo_t,   1024, 1024);
  transpose_w<<<dim3(4096/32, 1024/32), 256, 0, stream>>>(W1,   W1t,    1024, 4096);
  transpose_w<<<dim3(4096/32, 1024/32), 256, 0, stream>>>(W2,   W2t,    1024, 4096);
  transpose_w<<<dim3(1024/32, 4096/32), 256, 0, stream>>>(W3,   W3t,    4096, 1024);

  ln_kernel<<<MROWS, 256, 0, stream>>>(fin, vis, txt, aud, ln1g, ln1b, h);

  {  // QKV: M=8192, N=3072 -> 64x24 = 1536 blocks
    GemmP p{};
    p.A = h; p.Bt = Wqkv_t; p.K = 1024; p.N = 3072; p.bias = bqkv;
    p.oq = qh; p.ok = kh; p.ov = vhT;
    gemm_bn128<0><<<1536, 256, 0, stream>>>(p);
  }

  attn_kernel<<<2048, 256, 0, stream>>>(qh, kh, vhT, ctx);

  {  // proj + residual: N=1024 -> 512 blocks
    GemmP p{};
    p.A = ctx; p.Bt = Wo_t; p.K = 1024; p.N = 1024; p.bias = bo;
    p.r0 = fin; p.r1 = vis; p.r2 = txt; p.r3 = aud;
    p.of = x1;
    gemm_bn128<1><<<512, 256, 0, stream>>>(p);
  }

  ln_kernel<<<MROWS, 256, 0, stream>>>(x1, x1 + (size_t)2048 * 1024, x1 + (size_t)4096 * 1024,
                                       x1 + (size_t)6144 * 1024, ln2g, ln2b, h);

  // fused FFN up: silu(h@W1+b1)*(h@W2+b2) -> t1; 64x32 = 2048 blocks
  gemm_ffn<<<2048, 256, 0, stream>>>(h, W1t, W2t, b1, b2, t1);

  {  // FFN down + residual: N=1024, K=4096 -> 512 blocks
    GemmP p{};
    p.A = t1; p.Bt = W3t; p.K = HIDDIM; p.N = 1024; p.bias = b3;
    p.r0 = x1;
    p.of = (float*)d_out;
    gemm_bn128<4><<<512, 256, 0, stream>>>(p);
  }

  (void)in_sizes; (void)n_in; (void)out_size; (void)ws_size;
}

// Round 17
// 365.573 us; speedup vs baseline: 1.0770x; 1.0059x over previous
//
#include <hip/hip_runtime.h>

#define S_LEN  1024
#define DMODEL 1024
#define NHEAD  16
#define DHEAD  64
#define MROWS  8192   // 8 sequences * 1024
#define HIDDIM 4096
#define WINR   128

typedef __attribute__((ext_vector_type(8))) short bf16x8;
typedef __attribute__((ext_vector_type(4))) float f32x4;

__device__ __forceinline__ float bf2f(unsigned short u){ return __uint_as_float(((unsigned)u) << 16); }
__device__ __forceinline__ unsigned short f2bf(float f){
  unsigned u = __float_as_uint(f);
  u += 0x7FFFu + ((u >> 16) & 1u);
  return (unsigned short)(u >> 16);
}

// async global->LDS, 16 B per lane; lds dest is wave-uniform base (lane-linear fill)
__device__ __forceinline__ void gload_lds16(const unsigned short* g, unsigned short* l){
  __builtin_amdgcn_global_load_lds((const __attribute__((address_space(1))) unsigned int*)g,
                                   (__attribute__((address_space(3))) unsigned int*)l, 16, 0, 0);
}

// ---------------- weight transpose: in f32 [R][C] -> out bf16 [C][R] ----------------
__global__ __launch_bounds__(256) void transpose_w(const float* __restrict__ in,
                                                   unsigned short* __restrict__ out,
                                                   int R, int C){
  __shared__ float tile[32][33];
  const int c0 = blockIdx.x * 32;
  const int r0 = blockIdx.y * 32;
  const int tx = threadIdx.x & 31;
  const int ty = threadIdx.x >> 5;   // 0..7
  #pragma unroll
  for (int i = 0; i < 32; i += 8)
    tile[ty + i][tx] = in[(size_t)(r0 + ty + i) * C + c0 + tx];
  __syncthreads();
  #pragma unroll
  for (int i = 0; i < 32; i += 8)
    out[(size_t)(c0 + ty + i) * R + r0 + tx] = f2bf(tile[tx][ty + i]);
}

// ---------------- LayerNorm: row per block, 4 source pointers (2048 rows each) -------
__global__ __launch_bounds__(256) void ln_kernel(const float* __restrict__ s0, const float* __restrict__ s1,
                                                 const float* __restrict__ s2, const float* __restrict__ s3,
                                                 const float* __restrict__ g, const float* __restrict__ b,
                                                 unsigned short* __restrict__ out){
  const int row = blockIdx.x;
  const int t = threadIdx.x;
  const float* src = (row < 2048) ? s0 : (row < 4096) ? s1 : (row < 6144) ? s2 : s3;
  const float* x = src + (size_t)(row & 2047) * DMODEL;
  float4 v = *(const float4*)&x[t * 4];
  float sum  = v.x + v.y + v.z + v.w;
  float ssum = v.x*v.x + v.y*v.y + v.z*v.z + v.w*v.w;
  #pragma unroll
  for (int o = 32; o > 0; o >>= 1){
    sum  += __shfl_down(sum, o);
    ssum += __shfl_down(ssum, o);
  }
  __shared__ float red[8];
  if ((t & 63) == 0){ red[t >> 6] = sum; red[4 + (t >> 6)] = ssum; }
  __syncthreads();
  sum  = red[0] + red[1] + red[2] + red[3];
  ssum = red[4] + red[5] + red[6] + red[7];
  const float mu  = sum * (1.f / DMODEL);
  const float var = ssum * (1.f / DMODEL) - mu * mu;
  const float rs  = rsqrtf(var + 1e-5f);
  float4 gg = *(const float4*)&g[t * 4];
  float4 bb = *(const float4*)&b[t * 4];
  ushort4 o;
  o.x = f2bf((v.x - mu) * rs * gg.x + bb.x);
  o.y = f2bf((v.y - mu) * rs * gg.y + bb.y);
  o.z = f2bf((v.z - mu) * rs * gg.z + bb.z);
  o.w = f2bf((v.w - mu) * rs * gg.w + bb.w);
  *(ushort4*)&out[(size_t)row * DMODEL + t * 4] = o;
}

// ---------------- banded flash attention, MFMA 16x16x32, swapped QK^T ----------------
__global__ __launch_bounds__(256) void attn_kernel(const unsigned short* __restrict__ qh,
                                                   const unsigned short* __restrict__ kh,
                                                   const unsigned short* __restrict__ vt,
                                                   unsigned short* __restrict__ ctx){
  __shared__ unsigned short Ks[64 * 64];      // [key][d]  (d XOR-swizzled by key&7)
  __shared__ unsigned short Vs[64 * 64];      // [d][key]  (key XOR-swizzled by d&7)
  __shared__ unsigned short Ps[4][16 * 64];   // per-wave P [q][key] (key XOR by q&7)
  const int bx = blockIdx.x;
  const int qt = bx & 15, hd = (bx >> 4) & 15, n = bx >> 8;
  const int q0 = qt * 64;
  const int tid = threadIdx.x, lane = tid & 63, w = tid >> 6;
  const int hi = lane >> 4, lo = lane & 15;
  const size_t headoff = (size_t)(n * NHEAD + hd) * S_LEN * DHEAD;
  const unsigned short* kb = kh + headoff;
  const unsigned short* vb = vt + headoff;    // [64 d][1024 s]

  const int qg = q0 + w * 16 + lo;
  bf16x8 bq0 = *(const bf16x8*)(qh + headoff + (size_t)qg * DHEAD + hi * 8);
  bf16x8 bq1 = *(const bf16x8*)(qh + headoff + (size_t)qg * DHEAD + 32 + hi * 8);

  f32x4 oa[4];
  const f32x4 zero = {0.f, 0.f, 0.f, 0.f};
  #pragma unroll
  for (int dj = 0; dj < 4; dj++) oa[dj] = zero;
  float m = -20.f, lsum = 0.f;

  int t_first = q0 - WINR; if (t_first < 0) t_first = 0;
  int t_last  = q0 + 63 + WINR; if (t_last > S_LEN - 1) t_last = S_LEN - 1;

  const int sk = ((lane & 7) ^ (lane >> 3)) * 8;
  const int px = (lo & 7) * 8;

  for (int tb = t_first; tb <= t_last; tb += 64){
    __syncthreads();
    #pragma unroll
    for (int p = 0; p < 2; p++){
      const int r = w * 16 + p * 8 + (lane >> 3);
      gload_lds16(kb + (size_t)(tb + r) * DHEAD + sk, Ks + (w * 16 + p * 8) * 64);
      gload_lds16(vb + (size_t)r * S_LEN + tb + sk, Vs + (w * 16 + p * 8) * 64);
    }
    __syncthreads();

    f32x4 sc[4];
    #pragma unroll
    for (int j = 0; j < 4; j++){
      const int row = j * 16 + lo;
      bf16x8 ak0 = *(const bf16x8*)&Ks[row * 64 + ((hi * 8) ^ px)];
      bf16x8 ak1 = *(const bf16x8*)&Ks[row * 64 + ((32 + hi * 8) ^ px)];
      sc[j] = __builtin_amdgcn_mfma_f32_16x16x32_bf16(ak0, bq0, zero, 0, 0, 0);
      sc[j] = __builtin_amdgcn_mfma_f32_16x16x32_bf16(ak1, bq1, sc[j], 0, 0, 0);
    }

    float mloc = -1e30f;
    #pragma unroll
    for (int j = 0; j < 4; j++)
      #pragma unroll
      for (int r = 0; r < 4; r++){
        const int key = tb + j * 16 + hi * 4 + r;
        float s = sc[j][r] * 0.125f;
        s = ((unsigned)(key - qg + WINR) <= 2u * WINR) ? s : -1e9f;
        sc[j][r] = s;
        mloc = fmaxf(mloc, s);
      }
    mloc = fmaxf(mloc, __shfl_xor(mloc, 16));
    mloc = fmaxf(mloc, __shfl_xor(mloc, 32));
    const float nm = fmaxf(m, mloc);
    const float scale = __expf(m - nm);
    m = nm;
    float psum = 0.f;
    #pragma unroll
    for (int j = 0; j < 4; j++){
      float p0 = __expf(sc[j][0] - nm), p1 = __expf(sc[j][1] - nm);
      float p2 = __expf(sc[j][2] - nm), p3 = __expf(sc[j][3] - nm);
      psum += (p0 + p1) + (p2 + p3);
      ushort4 pw = { f2bf(p0), f2bf(p1), f2bf(p2), f2bf(p3) };
      *(ushort4*)&Ps[w][lo * 64 + ((hi * 4 + 16 * j) ^ px)] = pw;
    }
    psum += __shfl_xor(psum, 16);
    psum += __shfl_xor(psum, 32);
    lsum = lsum * scale + psum;

    float scr[4];
    #pragma unroll
    for (int r = 0; r < 4; r++) scr[r] = __shfl(scale, (lane & 48) + hi * 4 + r);
    #pragma unroll
    for (int dj = 0; dj < 4; dj++)
      #pragma unroll
      for (int r = 0; r < 4; r++) oa[dj][r] *= scr[r];

    bf16x8 pa0 = *(const bf16x8*)&Ps[w][lo * 64 + ((hi * 8) ^ px)];
    bf16x8 pa1 = *(const bf16x8*)&Ps[w][lo * 64 + ((32 + hi * 8) ^ px)];
    #pragma unroll
    for (int dj = 0; dj < 4; dj++){
      const int dr = dj * 16 + lo;
      bf16x8 bv0 = *(const bf16x8*)&Vs[dr * 64 + ((hi * 8) ^ px)];
      bf16x8 bv1 = *(const bf16x8*)&Vs[dr * 64 + ((32 + hi * 8) ^ px)];
      oa[dj] = __builtin_amdgcn_mfma_f32_16x16x32_bf16(pa0, bv0, oa[dj], 0, 0, 0);
      oa[dj] = __builtin_amdgcn_mfma_f32_16x16x32_bf16(pa1, bv1, oa[dj], 0, 0, 0);
    }
  }

  const float inv = 1.f / lsum;
  float invr[4];
  #pragma unroll
  for (int r = 0; r < 4; r++) invr[r] = __shfl(inv, (lane & 48) + hi * 4 + r);
  #pragma unroll
  for (int dj = 0; dj < 4; dj++)
    #pragma unroll
    for (int r = 0; r < 4; r++){
      const int srow = q0 + w * 16 + hi * 4 + r;
      ctx[((size_t)(n * S_LEN + srow)) * DMODEL + hd * DHEAD + dj * 16 + lo] =
          f2bf(oa[dj][r] * invr[r]);
    }
}

// ============ 128x128 bf16 MFMA GEMM, single-buffer 32 KB, L2 super-tiling ==========
// XCD chunk = 8 m-tiles x ntn n-tiles; traversed as 4m x 4n super-tiles (n-fastest
// supers): both operand panel sets stay L2-resident -> B re-fetched 2x/XCD not 8x.
struct GemmP {
  const unsigned short* A;
  const unsigned short* Bt;
  int K;
  int N;
  const float* bias;
  const float* r0; const float* r1; const float* r2; const float* r3;
  unsigned short* oq; unsigned short* ok; unsigned short* ov;   // qkv (ov = V^T)
  float* of;
};

// MODE 0: qkv head scatter (LDS-staged, V transposed)
// MODE 1: +bias +residual(sel by row) -> f32 direct float4
// MODE 4: +bias +r0 -> f32 direct float4
template<int MODE>
__global__ __launch_bounds__(256, 2) void gemm_bn128(GemmP p){
  __shared__ unsigned short ldsA[128 * 64];   // 16 KB
  __shared__ unsigned short ldsB[128 * 64];   // 16 KB
  const int tid  = threadIdx.x;
  const int lane = tid & 63;
  const int w    = tid >> 6;                // 0..3
  const int lo   = lane & 15, hi = lane >> 4;
  const int l3   = lane >> 3;
  const int sk   = ((lane & 7) ^ l3) * 8;   // pre-swizzled source k offset (elems)
  const int wm   = (w >> 1) * 64;           // 2M x 2N waves
  const int wn   = (w & 1) * 64;
  const int K    = p.K;

  // super-tiled XCD mapping: chunk-local c -> (srow, scol, m-in, n-in)
  const int ntn  = p.N >> 7;
  const int xcd  = (int)blockIdx.x & 7;
  const int c    = (int)blockIdx.x >> 3;    // 0..8*ntn-1
  const int nin  = c & 3;
  const int min_ = (c >> 2) & 3;
  const int s    = c >> 4;
  const int nsc  = ntn >> 2;                // super-cols
  const int scol = s % nsc;
  const int srow = s / nsc;
  const int m0   = (xcd * 8 + srow * 4 + min_) * 128;
  const int n0   = (scol * 4 + nin) * 128;

  f32x4 acc[4][4];
  const f32x4 zero = {0.f, 0.f, 0.f, 0.f};
  #pragma unroll
  for (int i = 0; i < 4; i++)
    #pragma unroll
    for (int j = 0; j < 4; j++) acc[i][j] = zero;

  const int NT = K >> 6;
  for (int T = 0; T < NT; T++){
    const int kb = T * 64;
    __syncthreads();             // prev-tile LDS reads done before overwrite
    #pragma unroll
    for (int cc = 0; cc < 4; cc++){
      const int r0 = w * 32 + cc * 8;       // 4 waves x 8 rows x 4 calls = 128 rows
      gload_lds16(p.A  + (size_t)(m0 + r0 + l3) * K + kb + sk, &ldsA[r0 * 64]);
      gload_lds16(p.Bt + (size_t)(n0 + r0 + l3) * K + kb + sk, &ldsB[r0 * 64]);
    }
    __syncthreads();             // drains vmcnt: this tile's stage visible to all

    #pragma unroll
    for (int kk = 0; kk < 2; kk++){
      bf16x8 af[4], bfr[4];
      #pragma unroll
      for (int i = 0; i < 4; i++){
        const int R = wm + i * 16 + lo;
        af[i] = *(const bf16x8*)&ldsA[R * 64 + (((kk * 4 + hi) ^ (R & 7)) * 8)];
      }
      #pragma unroll
      for (int j = 0; j < 4; j++){
        const int R = wn + j * 16 + lo;
        bfr[j] = *(const bf16x8*)&ldsB[R * 64 + (((kk * 4 + hi) ^ (R & 7)) * 8)];
      }
      #pragma unroll
      for (int i = 0; i < 4; i++)
        #pragma unroll
        for (int j = 0; j < 4; j++)
          acc[i][j] = __builtin_amdgcn_mfma_f32_16x16x32_bf16(bfr[j], af[i], acc[i][j], 0, 0, 0);
    }
  }

  if constexpr (MODE == 1 || MODE == 4){
    // direct coalesced f32: thread stores float4 (4 adjacent cols, one row)
    const float* rs = p.r0;
    if constexpr (MODE == 1){
      const int rblk = m0 + wm;   // uniform per wave, never straddles 2048
      rs = (rblk < 2048) ? p.r0 : (rblk < 4096) ? p.r1 : (rblk < 6144) ? p.r2 : p.r3;
    }
    #pragma unroll
    for (int i = 0; i < 4; i++){
      const int row = m0 + wm + i * 16 + lo;
      #pragma unroll
      for (int j = 0; j < 4; j++){
        const int cb = n0 + wn + j * 16 + hi * 4;
        float4 b4 = *(const float4*)&p.bias[cb];
        float4 r4;
        if constexpr (MODE == 1) r4 = *(const float4*)&rs[(size_t)(row & 2047) * DMODEL + cb];
        else                     r4 = *(const float4*)&rs[(size_t)row * DMODEL + cb];
        float4 v;
        v.x = acc[i][j][0] + b4.x + r4.x;
        v.y = acc[i][j][1] + b4.y + r4.y;
        v.z = acc[i][j][2] + b4.z + r4.z;
        v.w = acc[i][j][3] + b4.w + r4.w;
        *(float4*)&p.of[(size_t)row * DMODEL + cb] = v;
      }
    }
  } else {
    // MODE 0: LDS-staged coalesced qkv scatter (per-wave 8 KB slice spanning ldsA+ldsB)
    __syncthreads();                                  // all K-loop LDS reads done
    unsigned short* sl = &ldsA[0] + w * 4096;
    const int nseq = (m0 + wm) >> 10;                 // uniform per wave
    const int sof  = (m0 + wm) & 1023;
    const bool isV = (n0 >> 10) == 2;
    if (!isV){
      // stage [s 64][c 64], 16B-chunk XOR by row&7
      #pragma unroll
      for (int i = 0; i < 4; i++){
        const int row = i * 16 + lo;
        #pragma unroll
        for (int j = 0; j < 4; j++){
          const int cc = j * 16 + hi * 4;
          const int cb = n0 + wn + cc;
          float4 b4 = *(const float4*)&p.bias[cb];
          ushort4 o = { f2bf(acc[i][j][0] + b4.x), f2bf(acc[i][j][1] + b4.y),
                        f2bf(acc[i][j][2] + b4.z), f2bf(acc[i][j][3] + b4.w) };
          *(ushort4*)&sl[row * 64 + (((cc >> 3) ^ (row & 7)) * 8) + (cc & 7)] = o;
        }
      }
      asm volatile("s_waitcnt lgkmcnt(0)" ::: "memory");
      __builtin_amdgcn_sched_barrier(0);
      #pragma unroll
      for (int rep = 0; rep < 8; rep++){
        const int row = rep * 8 + l3;
        const int ch  = lane & 7;
        bf16x8 val = *(const bf16x8*)&sl[row * 64 + ((ch ^ (row & 7)) * 8)];
        const int cg = n0 + wn + ch * 8;
        const int hh = (cg & 1023) >> 6, d0 = cg & 63;
        unsigned short* dst = (cg >> 10) ? p.ok : p.oq;
        *(bf16x8*)&dst[((size_t)((nseq * NHEAD + hh) * S_LEN) + sof + row) * DHEAD + d0] = val;
      }
    } else {
      // V: stage transposed [d 64][s 64], 16B-chunk XOR by d&7
      #pragma unroll
      for (int i = 0; i < 4; i++){
        const int s2 = i * 16 + lo;
        #pragma unroll
        for (int j = 0; j < 4; j++){
          const int cb = n0 + wn + j * 16 + hi * 4;
          float4 b4 = *(const float4*)&p.bias[cb];
          #pragma unroll
          for (int r = 0; r < 4; r++){
            const int d = j * 16 + hi * 4 + r;
            const float bv = (r == 0) ? b4.x : (r == 1) ? b4.y : (r == 2) ? b4.z : b4.w;
            sl[d * 64 + (((s2 >> 3) ^ (d & 7)) * 8) + (s2 & 7)] = f2bf(acc[i][j][r] + bv);
          }
        }
      }
      asm volatile("s_waitcnt lgkmcnt(0)" ::: "memory");
      __builtin_amdgcn_sched_barrier(0);
      #pragma unroll
      for (int rep = 0; rep < 8; rep++){
        const int d  = rep * 8 + l3;
        const int ch = lane & 7;
        bf16x8 val = *(const bf16x8*)&sl[d * 64 + ((ch ^ (d & 7)) * 8)];
        const int cg = n0 + wn + d;
        const int hh = (cg & 1023) >> 6, dd = cg & 63;
        *(bf16x8*)&p.ov[((size_t)((nseq * NHEAD + hh) * DHEAD) + dd) * S_LEN + sof + ch * 8] = val;
      }
    }
  }
}

// ============ fused SwiGLU FFN-up: silu(A@W1^T+b1) * (A@W2^T+b2) -> bf16 =============
// Round-16 proven: 4m x 4n super-tiled XCD mapping (A 1MB + B 2MB < 4MB L2).
__global__ __launch_bounds__(256, 2) void gemm_ffn(const unsigned short* __restrict__ A,
                                                   const unsigned short* __restrict__ B1t,
                                                   const unsigned short* __restrict__ B2t,
                                                   const float* __restrict__ b1,
                                                   const float* __restrict__ b2,
                                                   unsigned short* __restrict__ out){
  __shared__ unsigned short ldsA[128 * 64];    // 16 KB
  __shared__ unsigned short ldsB1[128 * 64];   // 16 KB
  __shared__ unsigned short ldsB2[128 * 64];   // 16 KB
  const int tid  = threadIdx.x;
  const int lane = tid & 63;
  const int w    = tid >> 6;                // 0..3
  const int lo   = lane & 15, hi = lane >> 4;
  const int l3   = lane >> 3;
  const int sk   = ((lane & 7) ^ l3) * 8;
  const int wm   = (w >> 1) * 64;
  const int wn   = (w & 1) * 64;

  // XCD chunk (256 blocks = 8m x 32n) -> 4m x 4n super-tiles
  const int xcd = (int)blockIdx.x & 7;
  const int c   = (int)blockIdx.x >> 3;     // 0..255 chunk-local
  const int mt  = xcd * 8 + ((c >> 7) & 1) * 4 + ((c >> 2) & 3);   // m-tile 0..63
  const int nt  = ((c >> 4) & 7) * 4 + (c & 3);                    // n-tile 0..31
  const int m0  = mt * 128;
  const int n0  = nt * 128;

  f32x4 a1[4][4], a2[4][4];
  const f32x4 zero = {0.f, 0.f, 0.f, 0.f};
  #pragma unroll
  for (int i = 0; i < 4; i++)
    #pragma unroll
    for (int j = 0; j < 4; j++){ a1[i][j] = zero; a2[i][j] = zero; }

  const int NT = DMODEL >> 6;    // 16
  for (int T = 0; T < NT; T++){
    const int kb = T * 64;
    __syncthreads();             // prev-tile LDS reads done before overwrite
    #pragma unroll
    for (int cc = 0; cc < 4; cc++){
      const int r0 = w * 32 + cc * 8;
      gload_lds16(A   + (size_t)(m0 + r0 + l3) * DMODEL + kb + sk, &ldsA[r0 * 64]);
      gload_lds16(B1t + (size_t)(n0 + r0 + l3) * DMODEL + kb + sk, &ldsB1[r0 * 64]);
      gload_lds16(B2t + (size_t)(n0 + r0 + l3) * DMODEL + kb + sk, &ldsB2[r0 * 64]);
    }
    __syncthreads();             // drains vmcnt: this tile's stage visible to all

    #pragma unroll
    for (int kk = 0; kk < 2; kk++){
      bf16x8 af[4], bf1[4], bf2[4];
      #pragma unroll
      for (int i = 0; i < 4; i++){
        const int R = wm + i * 16 + lo;
        af[i] = *(const bf16x8*)&ldsA[R * 64 + (((kk * 4 + hi) ^ (R & 7)) * 8)];
      }
      #pragma unroll
      for (int j = 0; j < 4; j++){
        const int R = wn + j * 16 + lo;
        const int off = R * 64 + (((kk * 4 + hi) ^ (R & 7)) * 8);
        bf1[j] = *(const bf16x8*)&ldsB1[off];
        bf2[j] = *(const bf16x8*)&ldsB2[off];
      }
      #pragma unroll
      for (int i = 0; i < 4; i++)
        #pragma unroll
        for (int j = 0; j < 4; j++){
          a1[i][j] = __builtin_amdgcn_mfma_f32_16x16x32_bf16(bf1[j], af[i], a1[i][j], 0, 0, 0);
          a2[i][j] = __builtin_amdgcn_mfma_f32_16x16x32_bf16(bf2[j], af[i], a2[i][j], 0, 0, 0);
        }
    }
  }

  // fused epilogue: LDS-staged coalesced bf16 (per-wave 8 KB slice in ldsA+ldsB1)
  __syncthreads();
  unsigned short* sl = &ldsA[0] + w * 4096;
  #pragma unroll
  for (int i = 0; i < 4; i++){
    const int row = i * 16 + lo;
    #pragma unroll
    for (int j = 0; j < 4; j++){
      const int cc = j * 16 + hi * 4;
      const int cb = n0 + wn + cc;
      float4 g1 = *(const float4*)&b1[cb];
      float4 g2 = *(const float4*)&b2[cb];
      float v1[4] = { a1[i][j][0] + g1.x, a1[i][j][1] + g1.y, a1[i][j][2] + g1.z, a1[i][j][3] + g1.w };
      float v2[4] = { a2[i][j][0] + g2.x, a2[i][j][1] + g2.y, a2[i][j][2] + g2.z, a2[i][j][3] + g2.w };
      ushort4 o;
      o.x = f2bf(v1[0] / (1.f + __expf(-v1[0])) * v2[0]);
      o.y = f2bf(v1[1] / (1.f + __expf(-v1[1])) * v2[1]);
      o.z = f2bf(v1[2] / (1.f + __expf(-v1[2])) * v2[2]);
      o.w = f2bf(v1[3] / (1.f + __expf(-v1[3])) * v2[3]);
      *(ushort4*)&sl[row * 64 + (((cc >> 3) ^ (row & 7)) * 8) + (cc & 7)] = o;
    }
  }
  asm volatile("s_waitcnt lgkmcnt(0)" ::: "memory");
  __builtin_amdgcn_sched_barrier(0);
  #pragma unroll
  for (int rep = 0; rep < 8; rep++){
    const int row = rep * 8 + l3;
    const int ch  = lane & 7;
    bf16x8 val = *(const bf16x8*)&sl[row * 64 + ((ch ^ (row & 7)) * 8)];
    *(bf16x8*)&out[(size_t)(m0 + wm + row) * HIDDIM + n0 + wn + ch * 8] = val;
  }
}

// ------------------------------------------------------------------------------------
extern "C" void kernel_launch(void* const* d_in, const int* in_sizes, int n_in,
                              void* d_out, int out_size, void* d_ws, size_t ws_size,
                              hipStream_t stream){
  const float* fin  = (const float*)d_in[0];
  const float* vis  = (const float*)d_in[1];
  const float* txt  = (const float*)d_in[2];
  const float* aud  = (const float*)d_in[3];
  const float* ln1g = (const float*)d_in[4];
  const float* ln1b = (const float*)d_in[5];
  const float* Wqkv = (const float*)d_in[6];
  const float* bqkv = (const float*)d_in[7];
  const float* Wo   = (const float*)d_in[8];
  const float* bo   = (const float*)d_in[9];
  const float* ln2g = (const float*)d_in[10];
  const float* ln2b = (const float*)d_in[11];
  const float* W1   = (const float*)d_in[12];
  const float* b1   = (const float*)d_in[13];
  const float* W2   = (const float*)d_in[14];
  const float* b2   = (const float*)d_in[15];
  const float* W3   = (const float*)d_in[16];
  const float* b3   = (const float*)d_in[17];

  char* ws = (char*)d_ws;
  unsigned short* Wqkv_t = (unsigned short*)(ws + 0);          //  6,291,456
  unsigned short* Wo_t   = (unsigned short*)(ws + 6291456);    //  2,097,152
  unsigned short* W1t    = (unsigned short*)(ws + 8388608);    //  8,388,608
  unsigned short* W2t    = (unsigned short*)(ws + 16777216);   //  8,388,608
  unsigned short* W3t    = (unsigned short*)(ws + 25165824);   //  8,388,608
  unsigned short* h      = (unsigned short*)(ws + 33554432);   // 16,777,216
  unsigned short* qh     = (unsigned short*)(ws + 50331648);   // 16,777,216
  unsigned short* kh     = (unsigned short*)(ws + 67108864);   // 16,777,216
  unsigned short* vhT    = (unsigned short*)(ws + 83886080);   // 16,777,216  [n*h][64][1024]
  unsigned short* ctx    = (unsigned short*)(ws + 100663296);  // 16,777,216
  float*          x1     = (float*)(ws + 117440512);           // 33,554,432
  unsigned short* t1     = qh;  // [8192][4096] bf16, aliases qh..ctx (dead by FFN)

  transpose_w<<<dim3(3072/32, 1024/32), 256, 0, stream>>>(Wqkv, Wqkv_t, 1024, 3072);
  transpose_w<<<dim3(1024/32, 1024/32), 256, 0, stream>>>(Wo,   Wo_t,   1024, 1024);
  transpose_w<<<dim3(4096/32, 1024/32), 256, 0, stream>>>(W1,   W1t,    1024, 4096);
  transpose_w<<<dim3(4096/32, 1024/32), 256, 0, stream>>>(W2,   W2t,    1024, 4096);
  transpose_w<<<dim3(1024/32, 4096/32), 256, 0, stream>>>(W3,   W3t,    4096, 1024);

  ln_kernel<<<MROWS, 256, 0, stream>>>(fin, vis, txt, aud, ln1g, ln1b, h);

  {  // QKV: M=8192, N=3072 -> 64x24 = 1536 blocks
    GemmP p{};
    p.A = h; p.Bt = Wqkv_t; p.K = 1024; p.N = 3072; p.bias = bqkv;
    p.oq = qh; p.ok = kh; p.ov = vhT;
    gemm_bn128<0><<<1536, 256, 0, stream>>>(p);
  }

  attn_kernel<<<2048, 256, 0, stream>>>(qh, kh, vhT, ctx);

  {  // proj + residual: N=1024 -> 512 blocks
    GemmP p{};
    p.A = ctx; p.Bt = Wo_t; p.K = 1024; p.N = 1024; p.bias = bo;
    p.r0 = fin; p.r1 = vis; p.r2 = txt; p.r3 = aud;
    p.of = x1;
    gemm_bn128<1><<<512, 256, 0, stream>>>(p);
  }

  ln_kernel<<<MROWS, 256, 0, stream>>>(x1, x1 + (size_t)2048 * 1024, x1 + (size_t)4096 * 1024,
                                       x1 + (size_t)6144 * 1024, ln2g, ln2b, h);

  // fused FFN up: silu(h@W1+b1)*(h@W2+b2) -> t1; 64x32 = 2048 blocks
  gemm_ffn<<<2048, 256, 0, stream>>>(h, W1t, W2t, b1, b2, t1);

  {  // FFN down + residual: N=1024, K=4096 -> 512 blocks
    GemmP p{};
    p.A = t1; p.Bt = W3t; p.K = HIDDIM; p.N = 1024; p.bias = b3;
    p.r0 = x1;
    p.of = (float*)d_out;
    gemm_bn128<4><<<512, 256, 0, stream>>>(p);
  }

  (void)in_sizes; (void)n_in; (void)out_size; (void)ws_size;
}